// Round 17
// baseline (92.089 us; speedup 1.0000x reference)
//
#include <hip/hip_runtime.h>
#include <math.h>

#define B_ 8
#define C_ 64
#define M_ 512            // B_*C_
#define T_ 1200
#define TP2 1280          // T padded to 128
#define KP 4864           // K padded (K = 4800)
#define K2P 9728          // 2*KP interleaved cos/sin
#define SPLITK 8
#define KCH 1216          // K2P/SPLITK halves
#define NST1 20           // TP2/64 reduction steps (gemm1)
#define NST2 19           // KCH/64 reduction steps (gemm2)
#define TCH 152           // tau t-chunk length (8*152 = 1216)

#ifndef M_PI
#define M_PI 3.14159265358979323846
#endif

typedef _Float16 h8 __attribute__((ext_vector_type(8)));
typedef float f32x16 __attribute__((ext_vector_type(16)));
union H8 { h8 h; float4 v; _Float16 e[8]; };
union F4U { float4 v; float f[4]; };

#define Z16v {0.f,0.f,0.f,0.f,0.f,0.f,0.f,0.f,0.f,0.f,0.f,0.f,0.f,0.f,0.f,0.f}
#define MFMA32(a, b, c) __builtin_amdgcn_mfma_f32_32x32x16_f16(a, b, c, 0, 0, 0)

__device__ __forceinline__ float2 cmul(float2 a, float2 b) {
    return make_float2(a.x * b.x - a.y * b.y, a.y * b.x + a.x * b.y);
}

// async global->LDS, 16B per lane (dest resolves to wave base + lane*16)
__device__ __forceinline__ void gload16(const void* g, void* l) {
    __builtin_amdgcn_global_load_lds(
        (const __attribute__((address_space(1))) unsigned int*)g,
        (__attribute__((address_space(3))) unsigned int*)l, 16, 0, 0);
}

__device__ int detect_mode(const void* mask_raw) {
    __shared__ int sb0, sb1;
    if (threadIdx.x == 0) { sb0 = 0; sb1 = 0; }
    __syncthreads();
    const unsigned* wi = (const unsigned*)mask_raw;
    const float* wf = (const float*)mask_raw;
    int nw = (B_ * T_) >> 2;
    int badI = 0, badF = 0;
    for (int i = threadIdx.x; i < nw; i += blockDim.x) {
        unsigned v = wi[i];
        badI |= (v > 1u);
        float f = wf[i];
        badF |= !(f == 0.0f || f == 1.0f);
    }
    if (badI) sb0 = 1;
    if (badF) sb1 = 1;
    __syncthreads();
    return (!sb0) ? 0 : ((!sb1) ? 1 : 2);
}

__device__ __forceinline__ float mval(const void* mask_raw, int mode, int idx) {
    if (mode == 0) return (float)((const int*)mask_raw)[idx];
    if (mode == 1) return ((const float*)mask_raw)[idx];
    return (float)((const unsigned char*)mask_raw)[idx];
}

// omega rounded exactly as the reference: w = (double)(float)(2*pi*(fstep + k*fstep))
__device__ __forceinline__ double omega_w(int k, double fstep) {
    double om = 2.0 * M_PI * (fstep + (double)k * fstep);
    return (double)((float)om);
}

// ---------------- prep: dm (0..319) | tau (320..471) | cnt (472) ----------------
__global__ __launch_bounds__(256) void prep4_kernel(
    const float* __restrict__ data, const void* __restrict__ mask,
    float* __restrict__ cnt,
    _Float16* __restrict__ dm, float* __restrict__ partS, float* __restrict__ partC,
    double fstep) {
    __shared__ float mfS[B_][TCH];            // tau role
    int bx = blockIdx.x, tid = threadIdx.x;
    int mode = detect_mode(mask);
    if (bx < 320) {
        // dm: dm[bc][TP2] = f16(data*mask), 8 halves/thread, vectorized mask loads
        int base = (bx * 256 + tid) * 8;
        int t = base % TP2, bc = base / TP2;
        H8 o;
        if (t < T_) {
            int b = bc >> 6;
            int mi = b * T_ + t;           // multiple of 8 (1200 % 8 == 0)
            float mv[8];
            if (mode == 0) {
                int4 v0 = *(const int4*)((const int*)mask + mi);
                int4 v1 = *(const int4*)((const int*)mask + mi + 4);
                mv[0] = (float)v0.x; mv[1] = (float)v0.y; mv[2] = (float)v0.z; mv[3] = (float)v0.w;
                mv[4] = (float)v1.x; mv[5] = (float)v1.y; mv[6] = (float)v1.z; mv[7] = (float)v1.w;
            } else if (mode == 1) {
                F4U a0, a1;
                a0.v = *(const float4*)((const float*)mask + mi);
                a1.v = *(const float4*)((const float*)mask + mi + 4);
#pragma unroll
                for (int e = 0; e < 4; e++) { mv[e] = a0.f[e]; mv[e + 4] = a1.f[e]; }
            } else {
                uint2 u = *(const uint2*)((const unsigned char*)mask + mi);
#pragma unroll
                for (int e = 0; e < 4; e++) {
                    mv[e]     = (float)((u.x >> (8 * e)) & 0xff);
                    mv[e + 4] = (float)((u.y >> (8 * e)) & 0xff);
                }
            }
            F4U d0, d1;
            d0.v = *(const float4*)&data[bc * T_ + t];
            d1.v = *(const float4*)&data[bc * T_ + t + 4];
#pragma unroll
            for (int e = 0; e < 4; e++) {
                o.e[e]     = (_Float16)(d0.f[e] * mv[e]);
                o.e[e + 4] = (_Float16)(d1.f[e] * mv[e + 4]);
            }
        } else {
#pragma unroll
            for (int e = 0; e < 8; e++) o.e[e] = (_Float16)0.f;
        }
        *(float4*)&dm[base] = o.v;
        return;
    }
    if (bx < 472) {
        // tau partials; rot2/rot304 computed per-thread (2 dp sincos)
        int i0 = bx - 320;                    // 0..151
        int kb = i0 % 19, chunk = i0 / 19;    // 19 k-blocks x 8 chunks
        for (int i = tid; i < B_ * TCH; i += 256) {
            int b = i / TCH, tt = i % TCH;
            int t = chunk * TCH + tt;
            mfS[b][tt] = (t < T_) ? mval(mask, mode, b * T_ + t) : 0.f;
        }
        __syncthreads();
        int k = kb * 256 + tid;
        double w = omega_w(k, fstep);
        double ds, dc;
        sincos(2.0 * w, &ds, &dc);
        float2 r2 = make_float2((float)dc, (float)ds);
        sincos(304.0 * w, &ds, &dc);
        float2 r304 = make_float2((float)dc, (float)ds);
        float2 r = r2;
        {   // * rot304^chunk
            int e = chunk;
            float2 p = r304;
            while (e) { if (e & 1) r = cmul(r, p); p = cmul(p, p); e >>= 1; }
        }
        float s2a[B_], c2a[B_];
#pragma unroll
        for (int b = 0; b < B_; b++) { s2a[b] = 0.f; c2a[b] = 0.f; }
        for (int tt = 0; tt < TCH; tt++) {
            float sv = r.y, cv = r.x;
#pragma unroll
            for (int b = 0; b < B_; b++) {
                float m = mfS[b][tt];        // uniform address -> broadcast
                s2a[b] = fmaf(m, sv, s2a[b]);
                c2a[b] = fmaf(m, cv, c2a[b]);
            }
            r = cmul(r, r2);
        }
#pragma unroll
        for (int b = 0; b < B_; b++) {
            partS[(size_t)(chunk * 8 + b) * KP + k] = s2a[b];
            partC[(size_t)(chunk * 8 + b) * KP + k] = c2a[b];
        }
        return;
    }
    // bx == 472: cnt via per-b block reduction over raw mask
    {
        __shared__ float red[256];
        for (int b = 0; b < B_; b++) {
            float s = 0.f;
            for (int t = tid; t < T_; t += 256) s += mval(mask, mode, b * T_ + t);
            red[tid] = s; __syncthreads();
            for (int w = 128; w > 0; w >>= 1) {
                if (tid < w) red[tid] += red[tid + w];
                __syncthreads();
            }
            if (tid == 0) cnt[b] = red[0];
            __syncthreads();
        }
    }
}

// ---------------- GEMM1: 64(m) x 128(k2) tiles; B = basis generated in-kernel ----------------
// waves 2x2: wave tile 32(m) x 64(k2); epilogue phi + LS-combine
__global__ __launch_bounds__(256, 3) void gemm1x(
    const _Float16* __restrict__ dm,
    const float* __restrict__ partS, const float* __restrict__ partC,
    const float* __restrict__ cnt,
    _Float16* __restrict__ Wout, double fstep) {
    __shared__ _Float16 lds[24576];   // 48KB: 2 bufs x (A 8KB | B 16KB)
    char* ldsb = (char*)lds;
    int bx = blockIdx.x;                    // 608 = 8 XCD * 76
    int g = (bx & 7) * 76 + (bx >> 3);      // bijective, XCD-chunked
    int mt = g & 7, nt = g >> 3;
    int m0 = mt * 64, n0 = nt * 128;
    int tid = threadIdx.x, lane = tid & 63, wv = tid >> 6;
    int ra = lane & 31, kg = lane >> 5, x = ra & 7;
    int wm = (wv & 1) * 32, wn = (wv >> 1) * 64;
    int r0 = wm + ra, q0 = wn + ra;
    f32x16 acc0 = Z16v, acc1 = Z16v;
    // --- basis generation state: thread owns k = n0/2 + kk, t-lane tq*16..+15 ---
    int kk = tid >> 2, tq = tid & 3;
    double wth = omega_w((n0 >> 1) + kk, fstep);
    double sd_, cd_;
    sincos(wth * (double)(tq * 16 + 1), &sd_, &cd_);
    float2 pth = make_float2((float)cd_, (float)sd_);
    sincos(wth, &sd_, &cd_);
    float2 r1th = make_float2((float)cd_, (float)sd_);
    float2 r64th = r1th;
#pragma unroll
    for (int i = 0; i < 6; i++) r64th = cmul(r64th, r64th);   // r1^64
    // --- A staging offsets ---
    int sAo[2];
#pragma unroll
    for (int i = 0; i < 2; i++) {
        int g8 = i * 256 + tid;
        int r = g8 >> 3, c = g8 & 7;
        sAo[i] = r * 2560 + ((c ^ (r & 7)) << 4);
    }
    const char* pA = (const char*)dm + (size_t)m0 * 2560;
#define STG1A(BUFOFF, RC) do {                                                 \
        char* Ld_ = ldsb + (BUFOFF);                                           \
        _Pragma("unroll")                                                      \
        for (int i_ = 0; i_ < 2; i_++)                                         \
            gload16(pA + (RC) + sAo[i_], Ld_ + ((i_ * 256 + tid) << 4));       \
    } while (0)
#define GEN1(BUFOFF) do {                                                      \
        char* Bd_ = ldsb + (BUFOFF) + 8192;                                    \
        float2 q_ = pth;                                                       \
        H8 c0_, c1_, s0_, s1_;                                                 \
        _Pragma("unroll")                                                      \
        for (int j_ = 0; j_ < 8; j_++) {                                       \
            c0_.e[j_] = (_Float16)q_.x; s0_.e[j_] = (_Float16)q_.y;            \
            q_ = cmul(q_, r1th);                                               \
        }                                                                      \
        _Pragma("unroll")                                                      \
        for (int j_ = 0; j_ < 8; j_++) {                                       \
            c1_.e[j_] = (_Float16)q_.x; s1_.e[j_] = (_Float16)q_.y;            \
            q_ = cmul(q_, r1th);                                               \
        }                                                                      \
        int rc_ = 2 * kk, rs_ = rc_ + 1;                                       \
        *(float4*)(Bd_ + ((rc_ * 8 + ((tq * 2)     ^ (rc_ & 7))) << 4)) = c0_.v; \
        *(float4*)(Bd_ + ((rc_ * 8 + ((tq * 2 + 1) ^ (rc_ & 7))) << 4)) = c1_.v; \
        *(float4*)(Bd_ + ((rs_ * 8 + ((tq * 2)     ^ (rs_ & 7))) << 4)) = s0_.v; \
        *(float4*)(Bd_ + ((rs_ * 8 + ((tq * 2 + 1) ^ (rs_ & 7))) << 4)) = s1_.v; \
        pth = cmul(pth, r64th);                                                \
    } while (0)
    STG1A(0, 0);
    GEN1(0);
    __syncthreads();
    int cur = 0;
    for (int step = 0; step < NST1; step++) {
        if (step + 1 < NST1) {
            STG1A((cur ^ 1) * 24576, (step + 1) << 7);
            GEN1((cur ^ 1) * 24576);
        }
        const char* LA = ldsb + cur * 24576;
        const char* LB = LA + 8192;
#pragma unroll
        for (int kc = 0; kc < 4; kc++) {
            int c = kc * 2 + kg;
            h8 a0 = *(const h8*)(LA + ((r0 * 8 + (c ^ x)) << 4));
            h8 b0 = *(const h8*)(LB + ((q0 * 8 + (c ^ x)) << 4));
            h8 b1 = *(const h8*)(LB + (((q0 + 32) * 8 + (c ^ x)) << 4));
            acc0 = MFMA32(a0, b0, acc0);
            acc1 = MFMA32(a0, b1, acc1);
        }
        __syncthreads();
        cur ^= 1;
    }
#undef STG1A
#undef GEN1
    // epilogue: inline phi + LS-combine; wave owns rows m0+wm..+31, cols n0+wn..+63
    int bb = mt;                            // 64-row tile aligns with batch dim
    int colk = lane & 31, rb4 = (lane >> 5) * 4;
    float cn = cnt[bb];
    float cpJ[2], spJ[2], rcJ[2], rsJ[2];
#pragma unroll
    for (int J = 0; J < 2; J++) {
        int k2 = n0 + wn + 32 * J + colk;
        int k = k2 >> 1;
        float s2 = 0.f, c2 = 0.f;
#pragma unroll
        for (int c = 0; c < 8; c++) {
            s2 += partS[(size_t)(c * 8 + bb) * KP + k];
            c2 += partC[(size_t)(c * 8 + bb) * KP + k];
        }
        float phi = 0.5f * atan2f(s2, c2);
        float cp = cosf(phi), sp = sinf(phi);
        float A = 0.5f * (cn + c2), D = 0.5f * (cn - c2), E = 0.5f * s2;
        cpJ[J] = cp; spJ[J] = sp;
        rcJ[J] = 1.f / (cp * cp * A + 2.f * cp * sp * E + sp * sp * D);
        rsJ[J] = 1.f / (sp * sp * A - 2.f * cp * sp * E + cp * cp * D);
    }
#define EPI1(ACC, J) {                                                         \
        int k2 = n0 + wn + 32 * (J) + colk;                                    \
        float cp = cpJ[J], sp = spJ[J];                                        \
        float rc_ = rcJ[J], rs_ = rsJ[J];                                      \
        int par = k2 & 1;                                                      \
        _Pragma("unroll")                                                      \
        for (int reg = 0; reg < 16; reg++) {                                   \
            float own = (ACC)[reg];                                            \
            float oth = __shfl_xor(own, 1);                                    \
            float p = par ? oth : own, q = par ? own : oth;                    \
            float cc = (cp * p + sp * q) * rc_;                                \
            float sc = (cp * q - sp * p) * rs_;                                \
            float val = par ? (sp * cc + cp * sc) : (cp * cc - sp * sc);       \
            int row = m0 + wm + rb4 + (reg & 3) + 8 * (reg >> 2);              \
            Wout[(size_t)row * K2P + k2] = (_Float16)val;                      \
        } }
    EPI1(acc0, 0); EPI1(acc1, 1);
#undef EPI1
}

// ---------------- GEMM2: 128(m) x 64(t) tiles, split-K=8; B = basis^T generated ----------------
// waves 2x2: wave tile 64(m) x 32(t); rpart f16
__global__ __launch_bounds__(256, 3) void gemm2x(
    const _Float16* __restrict__ Wm,
    _Float16* __restrict__ rpart, int K, double fstep) {
    __shared__ _Float16 lds[24576];   // 48KB: 2 bufs x (A 16KB | B 8KB)
    char* ldsb = (char*)lds;
    int bx = blockIdx.x;                 // 640 = 8 XCD * 80; one sk per XCD
    int sk = bx & 7;
    int g2 = bx >> 3;                    // 0..79
    int mt = g2 & 3, tt = g2 >> 2;       // mt 0..3, tt 0..19
    int m0 = mt * 128, t0 = tt * 64;
    int tid = threadIdx.x, lane = tid & 63, wv = tid >> 6;
    int ra = lane & 31, kg = lane >> 5, x = ra & 7;
    int wm = (wv & 1) * 64, wn = (wv >> 1) * 32;
    int r0 = wm + ra, q0 = wn + ra;
    f32x16 acc0 = Z16v, acc1 = Z16v;
    // --- basis^T generation state: thread owns row t = t0+rt, k-lane kq*8..+7 ---
    int rt = tid >> 2, kq = tid & 3;
    int tp1 = t0 + rt + 1;
    int kth0 = sk * 608 + kq * 8;
    double w0 = omega_w(kth0, fstep);
    double sd_, cd_;
    sincos(w0 * (double)tp1, &sd_, &cd_);
    float2 pth = make_float2((float)cd_, (float)sd_);
    double s1d = 2.0 * M_PI * fstep * (double)tp1;
    sincos(s1d, &sd_, &cd_);
    float2 dlt = make_float2((float)cd_, (float)sd_);
    float2 d32 = dlt;
#pragma unroll
    for (int i = 0; i < 5; i++) d32 = cmul(d32, d32);   // delta^32
    // --- A staging offsets ---
    int sAo[4];
#pragma unroll
    for (int i = 0; i < 4; i++) {
        int g8 = i * 256 + tid;
        int r = g8 >> 3, c = g8 & 7;
        sAo[i] = r * 19456 + ((c ^ (r & 7)) << 4);
    }
    const char* pA = (const char*)Wm + (size_t)m0 * 19456 + sk * 2432;
#define STG2A(BUFOFF, RC) do {                                                 \
        char* Ld_ = ldsb + (BUFOFF);                                           \
        _Pragma("unroll")                                                      \
        for (int i_ = 0; i_ < 4; i_++)                                         \
            gload16(pA + (RC) + sAo[i_], Ld_ + ((i_ * 256 + tid) << 4));       \
    } while (0)
#define GEN2(BUFOFF, STEP) do {                                                \
        char* Bd_ = ldsb + (BUFOFF) + 16384;                                   \
        float2 q_ = pth;                                                       \
        int kc_ = kth0 + (STEP) * 32;                                          \
        H8 h0_, h1_;                                                           \
        _Pragma("unroll")                                                      \
        for (int j_ = 0; j_ < 4; j_++) {                                       \
            bool ok_ = (kc_ + j_) < K;                                         \
            h0_.e[2 * j_]     = (_Float16)(ok_ ? q_.x : 0.f);                  \
            h0_.e[2 * j_ + 1] = (_Float16)(ok_ ? q_.y : 0.f);                  \
            q_ = cmul(q_, dlt);                                                \
        }                                                                      \
        _Pragma("unroll")                                                      \
        for (int j_ = 0; j_ < 4; j_++) {                                       \
            bool ok_ = (kc_ + 4 + j_) < K;                                     \
            h1_.e[2 * j_]     = (_Float16)(ok_ ? q_.x : 0.f);                  \
            h1_.e[2 * j_ + 1] = (_Float16)(ok_ ? q_.y : 0.f);                  \
            q_ = cmul(q_, dlt);                                                \
        }                                                                      \
        *(float4*)(Bd_ + ((rt * 8 + ((kq * 2)     ^ (rt & 7))) << 4)) = h0_.v; \
        *(float4*)(Bd_ + ((rt * 8 + ((kq * 2 + 1) ^ (rt & 7))) << 4)) = h1_.v; \
        pth = cmul(pth, d32);                                                  \
    } while (0)
    STG2A(0, 0);
    GEN2(0, 0);
    __syncthreads();
    int cur = 0;
    for (int step = 0; step < NST2; step++) {
        if (step + 1 < NST2) {
            STG2A((cur ^ 1) * 24576, (step + 1) << 7);
            GEN2((cur ^ 1) * 24576, step + 1);
        }
        const char* LA = ldsb + cur * 24576;
        const char* LB = LA + 16384;
#pragma unroll
        for (int kc = 0; kc < 4; kc++) {
            int c = kc * 2 + kg;
            h8 a0 = *(const h8*)(LA + ((r0 * 8 + (c ^ x)) << 4));
            h8 a1 = *(const h8*)(LA + (((r0 + 32) * 8 + (c ^ x)) << 4));
            h8 b0 = *(const h8*)(LB + ((q0 * 8 + (c ^ x)) << 4));
            acc0 = MFMA32(a0, b0, acc0);
            acc1 = MFMA32(a1, b0, acc1);
        }
        __syncthreads();
        cur ^= 1;
    }
#undef STG2A
#undef GEN2
    int colk = lane & 31, rb4 = (lane >> 5) * 4;
    int t = t0 + wn + colk;
#define EPI2(ACC, I) {                                                         \
        _Pragma("unroll")                                                      \
        for (int reg = 0; reg < 16; reg++) {                                   \
            int row = m0 + wm + 32 * (I) + rb4 + (reg & 3) + 8 * (reg >> 2);   \
            rpart[(size_t)(sk * M_ + row) * TP2 + t] = (_Float16)(ACC)[reg];   \
        } }
    EPI2(acc0, 0); EPI2(acc1, 1);
#undef EPI2
}

// ---------------- normalize + select (f16 rpart, raw mask) ----------------
__global__ __launch_bounds__(256) void norm3_kernel(
    const _Float16* __restrict__ rpart, const float* __restrict__ data,
    const void* __restrict__ mask, const float* __restrict__ cnt,
    float* __restrict__ out) {
    int mode = detect_mode(mask);
    __shared__ float rsum[T_];
    __shared__ float4 red4[256];
    __shared__ float s_scale;
    int bc = blockIdx.x, b = bc >> 6;
    const size_t rbase = (size_t)bc * TP2;
    const size_t dbase = (size_t)bc * T_;
    const size_t rstr = (size_t)M_ * TP2;
    float sr = 0.f, srr = 0.f, sd = 0.f, sdd = 0.f;
    for (int t = threadIdx.x; t < T_; t += 256) {
        float r = 0.f;
#pragma unroll
        for (int s = 0; s < SPLITK; s++) r += (float)rpart[s * rstr + rbase + t];
        rsum[t] = r;
        float m = mval(mask, mode, b * T_ + t);
        float xv = data[dbase + t];
        sr += r; srr += r * r; sd += xv * m; sdd += xv * xv * m;
    }
    red4[threadIdx.x] = make_float4(sr, srr, sd, sdd);
    __syncthreads();
    for (int w = 128; w > 0; w >>= 1) {
        if (threadIdx.x < w) {
            float4 a = red4[threadIdx.x], c = red4[threadIdx.x + w];
            red4[threadIdx.x] = make_float4(a.x + c.x, a.y + c.y, a.z + c.z, a.w + c.w);
        }
        __syncthreads();
    }
    if (threadIdx.x == 0) {
        float4 v = red4[0];
        float cn = cnt[b];
        float varr = (v.y - v.x * v.x / (float)T_) / (float)(T_ - 1);
        float vard = (v.w - v.z * v.z / cn) / (cn - 1.f);
        s_scale = sqrtf(vard / varr);
    }
    __syncthreads();
    float scale = s_scale;
    for (int t = threadIdx.x; t < T_; t += 256) {
        float m = mval(mask, mode, b * T_ + t);
        out[dbase + t] = (m > 0.5f) ? data[dbase + t] : rsum[t] * scale;
    }
}

extern "C" void kernel_launch(void* const* d_in, const int* in_sizes, int n_in,
                              void* d_out, int out_size, void* d_ws, size_t ws_size,
                              hipStream_t stream) {
    const float* data = (const float*)d_in[0];
    const void* mask = d_in[1];
    float* out = (float*)d_out;

    // Replicate numpy arange length computation exactly (double precision).
    const double timespan = 1.0 * (T_ + 1) - 1.0;               // 1200
    const double fstep = 1.0 / (timespan * 8.0);                // OSFREQ = 8
    const double stop = (1.0 * (double)T_) / (2.0 * timespan) + fstep;
    const int K = (int)ceil((stop - fstep) / fstep);            // 4800 (or 4801)

    char* w = (char*)d_ws;
    auto alloc = [&](size_t nbytes) {
        char* p = w;
        w += ((nbytes + 255) / 256) * 256;
        return p;
    };
    float*     cnt   = (float*)    alloc(B_ * 4);
    float*     partS = (float*)    alloc((size_t)64 * KP * 4);
    float*     partC = (float*)    alloc((size_t)64 * KP * 4);
    _Float16*  dm_h  = (_Float16*) alloc((size_t)M_ * TP2 * 2);
    _Float16*  W     = (_Float16*) alloc((size_t)M_ * K2P * 2);
    _Float16*  rpart = (_Float16*) alloc((size_t)SPLITK * M_ * TP2 * 2);
    (void)ws_size; (void)in_sizes; (void)n_in; (void)out_size;

    prep4_kernel<<<473, 256, 0, stream>>>(data, mask, cnt, dm_h, partS, partC, fstep);
    gemm1x<<<608, 256, 0, stream>>>(dm_h, partS, partC, cnt, W, fstep);
    gemm2x<<<640, 256, 0, stream>>>(W, rpart, K, fstep);
    norm3_kernel<<<M_, 256, 0, stream>>>(rpart, data, mask, cnt, out);
}

// Round 18
// 90.453 us; speedup vs baseline: 1.0181x; 1.0181x over previous
//
#include <hip/hip_runtime.h>
#include <math.h>

#define B_ 8
#define C_ 64
#define M_ 512            // B_*C_
#define T_ 1200
#define TP2 1280          // T padded to 128
#define KP 4864           // K padded (K = 4800)
#define K2P 9728          // 2*KP interleaved cos/sin
#define SPLITK 8
#define KCH 1216          // K2P/SPLITK halves
#define NST1 20           // TP2/64 reduction steps (gemm1)
#define NST2 19           // KCH/64 reduction steps (gemm2)
#define TCH 152           // tau t-chunk length (8*152 = 1216)

#ifndef M_PI
#define M_PI 3.14159265358979323846
#endif

typedef _Float16 h8 __attribute__((ext_vector_type(8)));
typedef float f32x16 __attribute__((ext_vector_type(16)));
union H8 { h8 h; float4 v; _Float16 e[8]; };
union HP { _Float16 hh[2]; unsigned u; };
union F4U { float4 v; float f[4]; };

#define Z16v {0.f,0.f,0.f,0.f,0.f,0.f,0.f,0.f,0.f,0.f,0.f,0.f,0.f,0.f,0.f,0.f}
#define MFMA32(a, b, c) __builtin_amdgcn_mfma_f32_32x32x16_f16(a, b, c, 0, 0, 0)

__device__ __forceinline__ float2 cmul(float2 a, float2 b) {
    return make_float2(a.x * b.x - a.y * b.y, a.y * b.x + a.x * b.y);
}

// async global->LDS, 16B per lane (dest resolves to wave base + lane*16)
__device__ __forceinline__ void gload16(const void* g, void* l) {
    __builtin_amdgcn_global_load_lds(
        (const __attribute__((address_space(1))) unsigned int*)g,
        (__attribute__((address_space(3))) unsigned int*)l, 16, 0, 0);
}

__device__ int detect_mode(const void* mask_raw) {
    __shared__ int sb0, sb1;
    if (threadIdx.x == 0) { sb0 = 0; sb1 = 0; }
    __syncthreads();
    const unsigned* wi = (const unsigned*)mask_raw;
    const float* wf = (const float*)mask_raw;
    int nw = (B_ * T_) >> 2;
    int badI = 0, badF = 0;
    for (int i = threadIdx.x; i < nw; i += blockDim.x) {
        unsigned v = wi[i];
        badI |= (v > 1u);
        float f = wf[i];
        badF |= !(f == 0.0f || f == 1.0f);
    }
    if (badI) sb0 = 1;
    if (badF) sb1 = 1;
    __syncthreads();
    return (!sb0) ? 0 : ((!sb1) ? 1 : 2);
}

__device__ __forceinline__ float mval(const void* mask_raw, int mode, int idx) {
    if (mode == 0) return (float)((const int*)mask_raw)[idx];
    if (mode == 1) return ((const float*)mask_raw)[idx];
    return (float)((const unsigned char*)mask_raw)[idx];
}

// omega rounded exactly as the reference: w = (double)(float)(2*pi*(fstep + k*fstep))
__device__ __forceinline__ double omega_w(int k, double fstep) {
    double om = 2.0 * M_PI * (fstep + (double)k * fstep);
    return (double)((float)om);
}

// ---------------- prep3: dm (0..319, vectorized) | tau (320..471) | basisD (472..1991) | cnt (1992) ----------------
__global__ __launch_bounds__(256) void prep3_kernel(
    const float* __restrict__ data, const void* __restrict__ mask,
    float* __restrict__ cnt,
    _Float16* __restrict__ dm, float* __restrict__ partS, float* __restrict__ partC,
    _Float16* __restrict__ Zb, _Float16* __restrict__ ZT, int K, double fstep) {
    __shared__ float mfS[B_][TCH];            // tau role
    __shared__ _Float16 sZ[128 * 80];         // basisD role
    __shared__ _Float16 sZT[64 * 136];        // basisD role
    __shared__ float2 rotS[4][64];            // basisD role: rot{1,8,32,64}
    int bx = blockIdx.x, tid = threadIdx.x;
    if (bx < 320) {
        // dm: dm[bc][TP2] = f16(data*mask), 8 halves/thread, vectorized mask loads
        int mode = detect_mode(mask);
        int base = (bx * 256 + tid) * 8;
        int t = base % TP2, bc = base / TP2;
        H8 o;
        if (t < T_) {
            int b = bc >> 6;
            int mi = b * T_ + t;           // multiple of 8 (1200 % 8 == 0)
            float mv[8];
            if (mode == 0) {
                int4 v0 = *(const int4*)((const int*)mask + mi);
                int4 v1 = *(const int4*)((const int*)mask + mi + 4);
                mv[0] = (float)v0.x; mv[1] = (float)v0.y; mv[2] = (float)v0.z; mv[3] = (float)v0.w;
                mv[4] = (float)v1.x; mv[5] = (float)v1.y; mv[6] = (float)v1.z; mv[7] = (float)v1.w;
            } else if (mode == 1) {
                F4U a0, a1;
                a0.v = *(const float4*)((const float*)mask + mi);
                a1.v = *(const float4*)((const float*)mask + mi + 4);
#pragma unroll
                for (int e = 0; e < 4; e++) { mv[e] = a0.f[e]; mv[e + 4] = a1.f[e]; }
            } else {
                uint2 u = *(const uint2*)((const unsigned char*)mask + mi);
#pragma unroll
                for (int e = 0; e < 4; e++) {
                    mv[e]     = (float)((u.x >> (8 * e)) & 0xff);
                    mv[e + 4] = (float)((u.y >> (8 * e)) & 0xff);
                }
            }
            F4U d0, d1;
            d0.v = *(const float4*)&data[bc * T_ + t];
            d1.v = *(const float4*)&data[bc * T_ + t + 4];
#pragma unroll
            for (int e = 0; e < 4; e++) {
                o.e[e]     = (_Float16)(d0.f[e] * mv[e]);
                o.e[e + 4] = (_Float16)(d1.f[e] * mv[e + 4]);
            }
        } else {
#pragma unroll
            for (int e = 0; e < 8; e++) o.e[e] = (_Float16)0.f;
        }
        *(float4*)&dm[base] = o.v;
        return;
    }
    if (bx < 472) {
        // tau partials; rot2/rot304 computed per-thread (2 dp sincos)
        int mode = detect_mode(mask);
        int i0 = bx - 320;                    // 0..151
        int kb = i0 % 19, chunk = i0 / 19;    // 19 k-blocks x 8 chunks
        for (int i = tid; i < B_ * TCH; i += 256) {
            int b = i / TCH, tt = i % TCH;
            int t = chunk * TCH + tt;
            mfS[b][tt] = (t < T_) ? mval(mask, mode, b * T_ + t) : 0.f;
        }
        __syncthreads();
        int k = kb * 256 + tid;
        double w = omega_w(k, fstep);
        double ds, dc;
        sincos(2.0 * w, &ds, &dc);
        float2 r2 = make_float2((float)dc, (float)ds);
        sincos(304.0 * w, &ds, &dc);
        float2 r304 = make_float2((float)dc, (float)ds);
        float2 r = r2;
        {   // * rot304^chunk
            int e = chunk;
            float2 p = r304;
            while (e) { if (e & 1) r = cmul(r, p); p = cmul(p, p); e >>= 1; }
        }
        float s2a[B_], c2a[B_];
#pragma unroll
        for (int b = 0; b < B_; b++) { s2a[b] = 0.f; c2a[b] = 0.f; }
        for (int tt = 0; tt < TCH; tt++) {
            float sv = r.y, cv = r.x;
#pragma unroll
            for (int b = 0; b < B_; b++) {
                float m = mfS[b][tt];        // uniform address -> broadcast
                s2a[b] = fmaf(m, sv, s2a[b]);
                c2a[b] = fmaf(m, cv, c2a[b]);
            }
            r = cmul(r, r2);
        }
#pragma unroll
        for (int b = 0; b < B_; b++) {
            partS[(size_t)(chunk * 8 + b) * KP + k] = s2a[b];
            partC[(size_t)(chunk * 8 + b) * KP + k] = c2a[b];
        }
        return;
    }
    if (bx < 1992) {
        // basisD: Z[k2][t], ZT[t][k2], 64k x 64t tiles; rot via 1 dp sincos/thread
        int i0 = bx - 472;                    // 0..1519
        int kb = i0 / 20, tb = i0 % 20;
        int k0 = kb * 64, t0 = tb * 64;
        int kk = tid >> 2, tq = tid & 3;
        {
            // thread tid computes rot{mult[tq]} for k0+kk
            double w = omega_w(k0 + kk, fstep);
            double mult = (tq == 0) ? 1.0 : (tq == 1) ? 8.0 : (tq == 2) ? 32.0 : 64.0;
            double ds, dc;
            sincos(mult * w, &ds, &dc);
            rotS[tq][kk] = make_float2((float)dc, (float)ds);
        }
        __syncthreads();
        int k = k0 + kk;
        float2 r1 = rotS[0][kk];
        float2 acc = r1;                      // angle w*1
        {   // * rot8^tq
            float2 p = rotS[1][kk];
            if (tq & 1) acc = cmul(acc, p);
            p = cmul(p, p);
            if (tq & 2) acc = cmul(acc, p);
        }
        {   // * rot64^tb
            int e = tb;
            float2 p = rotS[3][kk];
            while (e) { if (e & 1) acc = cmul(acc, p); p = cmul(p, p); e >>= 1; }
        }
        bool kv = (k < K);
        float2 r32 = rotS[2][kk];
#pragma unroll
        for (int j = 0; j < 2; j++) {
            float2 r = acc;
            H8 hc, hs;
#pragma unroll
            for (int d = 0; d < 8; d++) {
                int tl = tq * 8 + j * 32 + d;
                bool ok = kv && (t0 + tl < T_);
                float c = ok ? r.x : 0.f, s = ok ? r.y : 0.f;
                hc.e[d] = (_Float16)c; hs.e[d] = (_Float16)s;
                HP pk; pk.hh[0] = hc.e[d]; pk.hh[1] = hs.e[d];
                *(unsigned*)&sZT[tl * 136 + 2 * kk] = pk.u;
                r = cmul(r, r1);
            }
            int ch = tq + 4 * j;              // chunk 0..7
            int rc = 2 * kk, rs = 2 * kk + 1;
            *(float4*)&sZ[rc * 80 + ((ch ^ (rc & 7)) << 3)] = hc.v;
            *(float4*)&sZ[rs * 80 + ((ch ^ (rs & 7)) << 3)] = hs.v;
            acc = cmul(acc, r32);
        }
        __syncthreads();
        // Z out: 128 rows x 128B
        {
            int c8 = tid & 7, rr = tid >> 3;  // rr 0..31
#pragma unroll
            for (int p = 0; p < 4; p++) {
                int row = p * 32 + rr;
                float4 v = *(const float4*)&sZ[row * 80 + ((c8 ^ (row & 7)) << 3)];
                *(float4*)&Zb[(size_t)(2 * k0 + row) * TP2 + t0 + c8 * 8] = v;
            }
        }
        // ZT out: 64 rows x 256B
        {
            int c16 = tid & 15, rr = tid >> 4; // rr 0..15
#pragma unroll
            for (int p = 0; p < 4; p++) {
                int row = p * 16 + rr;
                float4 v = *(const float4*)&sZT[row * 136 + c16 * 8];
                *(float4*)&ZT[(size_t)(t0 + row) * K2P + 2 * k0 + c16 * 8] = v;
            }
        }
        return;
    }
    // bx == 1992: cnt via per-b block reduction over raw mask
    {
        int mode = detect_mode(mask);
        __shared__ float red[256];
        for (int b = 0; b < B_; b++) {
            float s = 0.f;
            for (int t = tid; t < T_; t += 256) s += mval(mask, mode, b * T_ + t);
            red[tid] = s; __syncthreads();
            for (int w = 128; w > 0; w >>= 1) {
                if (tid < w) red[tid] += red[tid + w];
                __syncthreads();
            }
            if (tid == 0) cnt[b] = red[0];
            __syncthreads();
        }
    }
}

// ---------------- GEMM1: 64(m) x 128(k2) tiles, fused phi + LS-combine ----------------
// waves 2x2: wave tile 32(m) x 64(k2); 8 MFMA/step/wave
__global__ __launch_bounds__(256, 3) void gemm1x(
    const _Float16* __restrict__ dm, const _Float16* __restrict__ Zb,
    const float* __restrict__ partS, const float* __restrict__ partC,
    const float* __restrict__ cnt,
    _Float16* __restrict__ Wout) {
    __shared__ _Float16 lds[24576];   // 48KB: 2 bufs x (A 8KB | B 16KB)
    char* ldsb = (char*)lds;
    int bx = blockIdx.x;                    // 608 = 8 XCD * 76
    int g = (bx & 7) * 76 + (bx >> 3);      // bijective, XCD-chunked
    int mt = g & 7, nt = g >> 3;
    int m0 = mt * 64, n0 = nt * 128;
    int tid = threadIdx.x, lane = tid & 63, wv = tid >> 6;
    int ra = lane & 31, kg = lane >> 5, x = ra & 7;
    int wm = (wv & 1) * 32, wn = (wv >> 1) * 64;
    int r0 = wm + ra, q0 = wn + ra;
    f32x16 acc0 = Z16v, acc1 = Z16v;
    int sAo[2], sBo[4];
#pragma unroll
    for (int i = 0; i < 2; i++) {
        int g8 = i * 256 + tid;
        int r = g8 >> 3, c = g8 & 7;
        sAo[i] = r * 2560 + ((c ^ (r & 7)) << 4);
    }
#pragma unroll
    for (int i = 0; i < 4; i++) {
        int g8 = i * 256 + tid;
        int r = g8 >> 3, c = g8 & 7;
        sBo[i] = r * 2560 + ((c ^ (r & 7)) << 4);
    }
    const char* pA = (const char*)dm + (size_t)m0 * 2560;
    const char* pB = (const char*)Zb + (size_t)n0 * 2560;
#define STG1(BUFOFF, RC) do {                                                  \
        char* Ld_ = ldsb + (BUFOFF);                                           \
        _Pragma("unroll")                                                      \
        for (int i_ = 0; i_ < 2; i_++)                                         \
            gload16(pA + (RC) + sAo[i_], Ld_ + ((i_ * 256 + tid) << 4));       \
        _Pragma("unroll")                                                      \
        for (int i_ = 0; i_ < 4; i_++)                                         \
            gload16(pB + (RC) + sBo[i_], Ld_ + 8192 + ((i_ * 256 + tid) << 4));\
    } while (0)
    STG1(0, 0);
    __syncthreads();
    int cur = 0;
    for (int step = 0; step < NST1; step++) {
        if (step + 1 < NST1) STG1((cur ^ 1) * 24576, (step + 1) << 7);
        const char* LA = ldsb + cur * 24576;
        const char* LB = LA + 8192;
#pragma unroll
        for (int kc = 0; kc < 4; kc++) {
            int c = kc * 2 + kg;
            h8 a0 = *(const h8*)(LA + ((r0 * 8 + (c ^ x)) << 4));
            h8 b0 = *(const h8*)(LB + ((q0 * 8 + (c ^ x)) << 4));
            h8 b1 = *(const h8*)(LB + (((q0 + 32) * 8 + (c ^ x)) << 4));
            acc0 = MFMA32(a0, b0, acc0);
            acc1 = MFMA32(a0, b1, acc1);
        }
        __syncthreads();
        cur ^= 1;
    }
#undef STG1
    // epilogue: inline phi + LS-combine; wave owns rows m0+wm..+31, cols n0+wn..+63
    int bb = mt;                            // 64-row tile aligns with batch dim
    int colk = lane & 31, rb4 = (lane >> 5) * 4;
    float cn = cnt[bb];
    float cpJ[2], spJ[2], rcJ[2], rsJ[2];
#pragma unroll
    for (int J = 0; J < 2; J++) {
        int k2 = n0 + wn + 32 * J + colk;
        int k = k2 >> 1;
        float s2 = 0.f, c2 = 0.f;
#pragma unroll
        for (int c = 0; c < 8; c++) {
            s2 += partS[(size_t)(c * 8 + bb) * KP + k];
            c2 += partC[(size_t)(c * 8 + bb) * KP + k];
        }
        float phi = 0.5f * atan2f(s2, c2);
        float cp = cosf(phi), sp = sinf(phi);
        float A = 0.5f * (cn + c2), D = 0.5f * (cn - c2), E = 0.5f * s2;
        cpJ[J] = cp; spJ[J] = sp;
        rcJ[J] = 1.f / (cp * cp * A + 2.f * cp * sp * E + sp * sp * D);
        rsJ[J] = 1.f / (sp * sp * A - 2.f * cp * sp * E + cp * cp * D);
    }
#define EPI1(ACC, J) {                                                         \
        int k2 = n0 + wn + 32 * (J) + colk;                                    \
        float cp = cpJ[J], sp = spJ[J];                                        \
        float rc_ = rcJ[J], rs_ = rsJ[J];                                      \
        int par = k2 & 1;                                                      \
        _Pragma("unroll")                                                      \
        for (int reg = 0; reg < 16; reg++) {                                   \
            float own = (ACC)[reg];                                            \
            float oth = __shfl_xor(own, 1);                                    \
            float p = par ? oth : own, q = par ? own : oth;                    \
            float cc = (cp * p + sp * q) * rc_;                                \
            float sc = (cp * q - sp * p) * rs_;                                \
            float val = par ? (sp * cc + cp * sc) : (cp * cc - sp * sc);       \
            int row = m0 + wm + rb4 + (reg & 3) + 8 * (reg >> 2);              \
            Wout[(size_t)row * K2P + k2] = (_Float16)val;                      \
        } }
    EPI1(acc0, 0); EPI1(acc1, 1);
#undef EPI1
}

// ---------------- GEMM2: 128(m) x 64(t) tiles, split-K=8; rpart f16 ----------------
// waves 2x2: wave tile 64(m) x 32(t); 8 MFMA/step/wave
__global__ __launch_bounds__(256, 3) void gemm2x(
    const _Float16* __restrict__ Wm, const _Float16* __restrict__ ZT,
    _Float16* __restrict__ rpart) {
    __shared__ _Float16 lds[24576];   // 48KB: 2 bufs x (A 16KB | B 8KB)
    char* ldsb = (char*)lds;
    int bx = blockIdx.x;                 // 640 = 8 XCD * 80; one sk per XCD
    int sk = bx & 7;
    int g2 = bx >> 3;                    // 0..79
    int mt = g2 & 3, tt = g2 >> 2;       // mt 0..3, tt 0..19
    int m0 = mt * 128, t0 = tt * 64;
    int tid = threadIdx.x, lane = tid & 63, wv = tid >> 6;
    int ra = lane & 31, kg = lane >> 5, x = ra & 7;
    int wm = (wv & 1) * 64, wn = (wv >> 1) * 32;
    int r0 = wm + ra, q0 = wn + ra;
    f32x16 acc0 = Z16v, acc1 = Z16v;
    int sAo[4], sBo[2];
#pragma unroll
    for (int i = 0; i < 4; i++) {
        int g8 = i * 256 + tid;
        int r = g8 >> 3, c = g8 & 7;
        sAo[i] = r * 19456 + ((c ^ (r & 7)) << 4);
    }
#pragma unroll
    for (int i = 0; i < 2; i++) {
        int g8 = i * 256 + tid;
        int r = g8 >> 3, c = g8 & 7;
        sBo[i] = r * 19456 + ((c ^ (r & 7)) << 4);
    }
    const char* pA = (const char*)Wm + (size_t)m0 * 19456 + sk * 2432;
    const char* pB = (const char*)ZT + (size_t)t0 * 19456 + sk * 2432;
#define STG2(BUFOFF, RC) do {                                                  \
        char* Ld_ = ldsb + (BUFOFF);                                           \
        _Pragma("unroll")                                                      \
        for (int i_ = 0; i_ < 4; i_++)                                         \
            gload16(pA + (RC) + sAo[i_], Ld_ + ((i_ * 256 + tid) << 4));       \
        _Pragma("unroll")                                                      \
        for (int i_ = 0; i_ < 2; i_++)                                         \
            gload16(pB + (RC) + sBo[i_], Ld_ + 16384 + ((i_ * 256 + tid) << 4));\
    } while (0)
    STG2(0, 0);
    __syncthreads();
    int cur = 0;
    for (int step = 0; step < NST2; step++) {
        if (step + 1 < NST2) STG2((cur ^ 1) * 24576, (step + 1) << 7);
        const char* LA = ldsb + cur * 24576;
        const char* LB = LA + 16384;
#pragma unroll
        for (int kc = 0; kc < 4; kc++) {
            int c = kc * 2 + kg;
            h8 a0 = *(const h8*)(LA + ((r0 * 8 + (c ^ x)) << 4));
            h8 a1 = *(const h8*)(LA + (((r0 + 32) * 8 + (c ^ x)) << 4));
            h8 b0 = *(const h8*)(LB + ((q0 * 8 + (c ^ x)) << 4));
            acc0 = MFMA32(a0, b0, acc0);
            acc1 = MFMA32(a1, b0, acc1);
        }
        __syncthreads();
        cur ^= 1;
    }
#undef STG2
    int colk = lane & 31, rb4 = (lane >> 5) * 4;
    int t = t0 + wn + colk;
#define EPI2(ACC, I) {                                                         \
        _Pragma("unroll")                                                      \
        for (int reg = 0; reg < 16; reg++) {                                   \
            int row = m0 + wm + 32 * (I) + rb4 + (reg & 3) + 8 * (reg >> 2);   \
            rpart[(size_t)(sk * M_ + row) * TP2 + t] = (_Float16)(ACC)[reg];   \
        } }
    EPI2(acc0, 0); EPI2(acc1, 1);
#undef EPI2
}

// ---------------- normalize + select (f16 rpart, raw mask) ----------------
__global__ __launch_bounds__(256) void norm3_kernel(
    const _Float16* __restrict__ rpart, const float* __restrict__ data,
    const void* __restrict__ mask, const float* __restrict__ cnt,
    float* __restrict__ out) {
    int mode = detect_mode(mask);
    __shared__ float rsum[T_];
    __shared__ float4 red4[256];
    __shared__ float s_scale;
    int bc = blockIdx.x, b = bc >> 6;
    const size_t rbase = (size_t)bc * TP2;
    const size_t dbase = (size_t)bc * T_;
    const size_t rstr = (size_t)M_ * TP2;
    float sr = 0.f, srr = 0.f, sd = 0.f, sdd = 0.f;
    for (int t = threadIdx.x; t < T_; t += 256) {
        float r = 0.f;
#pragma unroll
        for (int s = 0; s < SPLITK; s++) r += (float)rpart[s * rstr + rbase + t];
        rsum[t] = r;
        float m = mval(mask, mode, b * T_ + t);
        float xv = data[dbase + t];
        sr += r; srr += r * r; sd += xv * m; sdd += xv * xv * m;
    }
    red4[threadIdx.x] = make_float4(sr, srr, sd, sdd);
    __syncthreads();
    for (int w = 128; w > 0; w >>= 1) {
        if (threadIdx.x < w) {
            float4 a = red4[threadIdx.x], c = red4[threadIdx.x + w];
            red4[threadIdx.x] = make_float4(a.x + c.x, a.y + c.y, a.z + c.z, a.w + c.w);
        }
        __syncthreads();
    }
    if (threadIdx.x == 0) {
        float4 v = red4[0];
        float cn = cnt[b];
        float varr = (v.y - v.x * v.x / (float)T_) / (float)(T_ - 1);
        float vard = (v.w - v.z * v.z / cn) / (cn - 1.f);
        s_scale = sqrtf(vard / varr);
    }
    __syncthreads();
    float scale = s_scale;
    for (int t = threadIdx.x; t < T_; t += 256) {
        float m = mval(mask, mode, b * T_ + t);
        out[dbase + t] = (m > 0.5f) ? data[dbase + t] : rsum[t] * scale;
    }
}

extern "C" void kernel_launch(void* const* d_in, const int* in_sizes, int n_in,
                              void* d_out, int out_size, void* d_ws, size_t ws_size,
                              hipStream_t stream) {
    const float* data = (const float*)d_in[0];
    const void* mask = d_in[1];
    float* out = (float*)d_out;

    // Replicate numpy arange length computation exactly (double precision).
    const double timespan = 1.0 * (T_ + 1) - 1.0;               // 1200
    const double fstep = 1.0 / (timespan * 8.0);                // OSFREQ = 8
    const double stop = (1.0 * (double)T_) / (2.0 * timespan) + fstep;
    const int K = (int)ceil((stop - fstep) / fstep);            // 4800 (or 4801)

    char* w = (char*)d_ws;
    auto alloc = [&](size_t nbytes) {
        char* p = w;
        w += ((nbytes + 255) / 256) * 256;
        return p;
    };
    float*     cnt   = (float*)    alloc(B_ * 4);
    float*     partS = (float*)    alloc((size_t)64 * KP * 4);
    float*     partC = (float*)    alloc((size_t)64 * KP * 4);
    _Float16*  dm_h  = (_Float16*) alloc((size_t)M_ * TP2 * 2);
    _Float16*  Z     = (_Float16*) alloc((size_t)K2P * TP2 * 2);
    _Float16*  ZT    = (_Float16*) alloc((size_t)TP2 * K2P * 2);
    _Float16*  W     = (_Float16*) alloc((size_t)M_ * K2P * 2);
    _Float16*  rpart = (_Float16*) alloc((size_t)SPLITK * M_ * TP2 * 2);
    (void)ws_size; (void)in_sizes; (void)n_in; (void)out_size;

    prep3_kernel<<<1993, 256, 0, stream>>>(data, mask, cnt, dm_h, partS, partC,
                                           Z, ZT, K, fstep);
    gemm1x<<<608, 256, 0, stream>>>(dm_h, Z, partS, partC, cnt, W);
    gemm2x<<<640, 256, 0, stream>>>(W, ZT, rpart);
    norm3_kernel<<<M_, 256, 0, stream>>>(rpart, data, mask, cnt, out);
}

// Round 19
// 89.492 us; speedup vs baseline: 1.0290x; 1.0107x over previous
//
#include <hip/hip_runtime.h>
#include <math.h>

#define B_ 8
#define C_ 64
#define M_ 512            // B_*C_
#define T_ 1200
#define TP2 1280          // T padded to 128
#define KP 4864           // K padded (K = 4800)
#define K2P 9728          // 2*KP interleaved cos/sin
#define SPLITK 8
#define KCH 1216          // K2P/SPLITK halves
#define NST1 20           // TP2/64 reduction steps (gemm1)
#define NST2 19           // KCH/64 reduction steps (gemm2)
#define TCH 152           // tau t-chunk length (8*152 = 1216)

#ifndef M_PI
#define M_PI 3.14159265358979323846
#endif

typedef _Float16 h8 __attribute__((ext_vector_type(8)));
typedef float f32x16 __attribute__((ext_vector_type(16)));
union H8 { h8 h; float4 v; _Float16 e[8]; };
union HP { _Float16 hh[2]; unsigned u; };
union F4U { float4 v; float f[4]; };

#define Z16v {0.f,0.f,0.f,0.f,0.f,0.f,0.f,0.f,0.f,0.f,0.f,0.f,0.f,0.f,0.f,0.f}
#define MFMA32(a, b, c) __builtin_amdgcn_mfma_f32_32x32x16_f16(a, b, c, 0, 0, 0)

__device__ __forceinline__ float2 cmul(float2 a, float2 b) {
    return make_float2(a.x * b.x - a.y * b.y, a.y * b.x + a.x * b.y);
}

// async global->LDS, 16B per lane (dest resolves to wave base + lane*16)
__device__ __forceinline__ void gload16(const void* g, void* l) {
    __builtin_amdgcn_global_load_lds(
        (const __attribute__((address_space(1))) unsigned int*)g,
        (__attribute__((address_space(3))) unsigned int*)l, 16, 0, 0);
}

__device__ int detect_mode(const void* mask_raw) {
    __shared__ int sb0, sb1;
    if (threadIdx.x == 0) { sb0 = 0; sb1 = 0; }
    __syncthreads();
    const unsigned* wi = (const unsigned*)mask_raw;
    const float* wf = (const float*)mask_raw;
    int nw = (B_ * T_) >> 2;
    int badI = 0, badF = 0;
    for (int i = threadIdx.x; i < nw; i += blockDim.x) {
        unsigned v = wi[i];
        badI |= (v > 1u);
        float f = wf[i];
        badF |= !(f == 0.0f || f == 1.0f);
    }
    if (badI) sb0 = 1;
    if (badF) sb1 = 1;
    __syncthreads();
    return (!sb0) ? 0 : ((!sb1) ? 1 : 2);
}

__device__ __forceinline__ float mval(const void* mask_raw, int mode, int idx) {
    if (mode == 0) return (float)((const int*)mask_raw)[idx];
    if (mode == 1) return ((const float*)mask_raw)[idx];
    return (float)((const unsigned char*)mask_raw)[idx];
}

// ---------------- K1 seed: rot tables (0..113) | mf (114..123) | cnt (124) ----------------
__global__ __launch_bounds__(256) void seed_kernel(
    const void* __restrict__ mask, float* __restrict__ mf, float* __restrict__ cnt,
    float2* __restrict__ rot1, float2* __restrict__ rot8,
    float2* __restrict__ rot32, float2* __restrict__ rot64,
    float2* __restrict__ rot2, float2* __restrict__ rot304, double fstep) {
    int bx = blockIdx.x, tid = threadIdx.x;
    if (bx < 114) {
        int tb = bx / 19;
        int k = (bx % 19) * 256 + tid;     // < 4864
        double om = 2.0 * M_PI * (fstep + (double)k * fstep);
        double w = (double)((float)om);    // reference rounds omega to f32
        double mult = (tb == 0) ? 1.0 : (tb == 1) ? 8.0 : (tb == 2) ? 32.0
                    : (tb == 3) ? 64.0 : (tb == 4) ? 2.0 : 304.0;
        double s, c;
        sincos(mult * w, &s, &c);
        float2 v = make_float2((float)c, (float)s);
        if (tb == 0)      rot1[k] = v;
        else if (tb == 1) rot8[k] = v;
        else if (tb == 2) rot32[k] = v;
        else if (tb == 3) rot64[k] = v;
        else if (tb == 4) rot2[k] = v;
        else              rot304[k] = v;
        return;
    }
    int mode = detect_mode(mask);
    if (bx < 124) {
        // mf convert, vectorized
        int i = ((bx - 114) * 256 + tid) * 4;   // 10 blocks cover 9600
        if (i >= B_ * T_) return;
        F4U o;
        if (mode == 0) {
            int4 v = *(const int4*)((const int*)mask + i);
            o.f[0] = (float)v.x; o.f[1] = (float)v.y; o.f[2] = (float)v.z; o.f[3] = (float)v.w;
        } else if (mode == 1) {
            o.v = *(const float4*)((const float*)mask + i);
        } else {
            unsigned v = *(const unsigned*)((const unsigned char*)mask + i);
            o.f[0] = (float)(v & 0xff); o.f[1] = (float)((v >> 8) & 0xff);
            o.f[2] = (float)((v >> 16) & 0xff); o.f[3] = (float)((v >> 24) & 0xff);
        }
        *(float4*)&mf[i] = o.v;
        return;
    }
    // bx == 124: cnt via per-b block reduction over raw mask (no atomics)
    {
        __shared__ float red[256];
        for (int b = 0; b < B_; b++) {
            float s = 0.f;
            for (int t = tid; t < T_; t += 256) s += mval(mask, mode, b * T_ + t);
            red[tid] = s; __syncthreads();
            for (int w = 128; w > 0; w >>= 1) {
                if (tid < w) red[tid] += red[tid + w];
                __syncthreads();
            }
            if (tid == 0) cnt[b] = red[0];
            __syncthreads();
        }
    }
}

// ---------------- K2 prep2: dm (0..319) | tau (320..471) | basisD (472..1991) ----------------
__global__ __launch_bounds__(256) void prep2_kernel(
    const float* __restrict__ data, const float* __restrict__ mf,
    const float2* __restrict__ rot1t, const float2* __restrict__ rot8t,
    const float2* __restrict__ rot32t, const float2* __restrict__ rot64t,
    const float2* __restrict__ rot2t, const float2* __restrict__ rot304t,
    _Float16* __restrict__ dm, float* __restrict__ partS, float* __restrict__ partC,
    _Float16* __restrict__ Zb, _Float16* __restrict__ ZT, int K) {
    __shared__ float mfS[B_][TCH];            // tau role
    __shared__ _Float16 sZ[128 * 80];         // basisD role
    __shared__ _Float16 sZT[64 * 136];        // basisD role
    int bx = blockIdx.x, tid = threadIdx.x;
    if (bx < 320) {
        // dm: dm[bc][TP2] = f16(data*mf), 8 halves/thread
        int base = (bx * 256 + tid) * 8;
        int t = base % TP2, bc = base / TP2;
        H8 o;
        if (t < T_) {
            int b = bc >> 6;
            F4U d0, d1, m0, m1;
            d0.v = *(const float4*)&data[bc * T_ + t];
            d1.v = *(const float4*)&data[bc * T_ + t + 4];
            m0.v = *(const float4*)&mf[b * T_ + t];
            m1.v = *(const float4*)&mf[b * T_ + t + 4];
#pragma unroll
            for (int e = 0; e < 4; e++) {
                o.e[e]     = (_Float16)(d0.f[e] * m0.f[e]);
                o.e[e + 4] = (_Float16)(d1.f[e] * m1.f[e]);
            }
        } else {
#pragma unroll
            for (int e = 0; e < 8; e++) o.e[e] = (_Float16)0.f;
        }
        *(float4*)&dm[base] = o.v;
        return;
    }
    if (bx < 472) {
        // tau partials
        int i0 = bx - 320;                    // 0..151
        int kb = i0 % 19, chunk = i0 / 19;    // 19 k-blocks x 8 chunks
        for (int i = tid; i < B_ * TCH; i += 256) {
            int b = i / TCH, tt = i % TCH;
            int t = chunk * TCH + tt;
            mfS[b][tt] = (t < T_) ? mf[b * T_ + t] : 0.f;
        }
        __syncthreads();
        int k = kb * 256 + tid;
        float2 r2 = rot2t[k];
        float2 r = r2;
        {   // * rot304^chunk
            int e = chunk;
            float2 p = rot304t[k];
            while (e) { if (e & 1) r = cmul(r, p); p = cmul(p, p); e >>= 1; }
        }
        float s2a[B_], c2a[B_];
#pragma unroll
        for (int b = 0; b < B_; b++) { s2a[b] = 0.f; c2a[b] = 0.f; }
        for (int tt = 0; tt < TCH; tt++) {
            float sv = r.y, cv = r.x;
#pragma unroll
            for (int b = 0; b < B_; b++) {
                float m = mfS[b][tt];        // uniform address -> broadcast
                s2a[b] = fmaf(m, sv, s2a[b]);
                c2a[b] = fmaf(m, cv, c2a[b]);
            }
            r = cmul(r, r2);
        }
#pragma unroll
        for (int b = 0; b < B_; b++) {
            partS[(size_t)(chunk * 8 + b) * KP + k] = s2a[b];
            partC[(size_t)(chunk * 8 + b) * KP + k] = c2a[b];
        }
        return;
    }
    // basisD: Z[k2][t], ZT[t][k2], 64k x 64t tiles
    {
        int i0 = bx - 472;                    // 0..1519
        int kb = i0 / 20, tb = i0 % 20;
        int k0 = kb * 64, t0 = tb * 64;
        int kk = tid >> 2, tq = tid & 3;
        int k = k0 + kk;
        float2 r1 = rot1t[k];
        float2 acc = r1;                      // angle w*1
        {   // * rot8^tq
            float2 p = rot8t[k];
            if (tq & 1) acc = cmul(acc, p);
            p = cmul(p, p);
            if (tq & 2) acc = cmul(acc, p);
        }
        {   // * rot64^tb
            int e = tb;
            float2 p = rot64t[k];
            while (e) { if (e & 1) acc = cmul(acc, p); p = cmul(p, p); e >>= 1; }
        }
        bool kv = (k < K);
        float2 r32 = rot32t[k];
#pragma unroll
        for (int j = 0; j < 2; j++) {
            float2 r = acc;
            H8 hc, hs;
#pragma unroll
            for (int d = 0; d < 8; d++) {
                int tl = tq * 8 + j * 32 + d;
                bool ok = kv && (t0 + tl < T_);
                float c = ok ? r.x : 0.f, s = ok ? r.y : 0.f;
                hc.e[d] = (_Float16)c; hs.e[d] = (_Float16)s;
                HP pk; pk.hh[0] = hc.e[d]; pk.hh[1] = hs.e[d];
                *(unsigned*)&sZT[tl * 136 + 2 * kk] = pk.u;
                r = cmul(r, r1);
            }
            int ch = tq + 4 * j;              // chunk 0..7
            int rc = 2 * kk, rs = 2 * kk + 1;
            *(float4*)&sZ[rc * 80 + ((ch ^ (rc & 7)) << 3)] = hc.v;
            *(float4*)&sZ[rs * 80 + ((ch ^ (rs & 7)) << 3)] = hs.v;
            acc = cmul(acc, r32);
        }
        __syncthreads();
        // Z out: 128 rows x 128B
        {
            int c8 = tid & 7, rr = tid >> 3;  // rr 0..31
#pragma unroll
            for (int p = 0; p < 4; p++) {
                int row = p * 32 + rr;
                float4 v = *(const float4*)&sZ[row * 80 + ((c8 ^ (row & 7)) << 3)];
                *(float4*)&Zb[(size_t)(2 * k0 + row) * TP2 + t0 + c8 * 8] = v;
            }
        }
        // ZT out: 64 rows x 256B
        {
            int c16 = tid & 15, rr = tid >> 4; // rr 0..15
#pragma unroll
            for (int p = 0; p < 4; p++) {
                int row = p * 16 + rr;
                float4 v = *(const float4*)&sZT[row * 136 + c16 * 8];
                *(float4*)&ZT[(size_t)(t0 + row) * K2P + 2 * k0 + c16 * 8] = v;
            }
        }
    }
}

// ---------------- GEMM1: 64(m) x 128(k2) tiles, fused phi + LS-combine ----------------
// waves 2x2: wave tile 32(m) x 64(k2); 8 MFMA/step/wave
__global__ __launch_bounds__(256, 3) void gemm1x(
    const _Float16* __restrict__ dm, const _Float16* __restrict__ Zb,
    const float* __restrict__ partS, const float* __restrict__ partC,
    const float* __restrict__ cnt,
    _Float16* __restrict__ Wout) {
    __shared__ _Float16 lds[24576];   // 48KB: 2 bufs x (A 8KB | B 16KB)
    char* ldsb = (char*)lds;
    int bx = blockIdx.x;                    // 608 = 8 XCD * 76
    int g = (bx & 7) * 76 + (bx >> 3);      // bijective, XCD-chunked
    int mt = g & 7, nt = g >> 3;
    int m0 = mt * 64, n0 = nt * 128;
    int tid = threadIdx.x, lane = tid & 63, wv = tid >> 6;
    int ra = lane & 31, kg = lane >> 5, x = ra & 7;
    int wm = (wv & 1) * 32, wn = (wv >> 1) * 64;
    int r0 = wm + ra, q0 = wn + ra;
    f32x16 acc0 = Z16v, acc1 = Z16v;
    int sAo[2], sBo[4];
#pragma unroll
    for (int i = 0; i < 2; i++) {
        int g8 = i * 256 + tid;
        int r = g8 >> 3, c = g8 & 7;
        sAo[i] = r * 2560 + ((c ^ (r & 7)) << 4);
    }
#pragma unroll
    for (int i = 0; i < 4; i++) {
        int g8 = i * 256 + tid;
        int r = g8 >> 3, c = g8 & 7;
        sBo[i] = r * 2560 + ((c ^ (r & 7)) << 4);
    }
    const char* pA = (const char*)dm + (size_t)m0 * 2560;
    const char* pB = (const char*)Zb + (size_t)n0 * 2560;
#define STG1(BUFOFF, RC) do {                                                  \
        char* Ld_ = ldsb + (BUFOFF);                                           \
        _Pragma("unroll")                                                      \
        for (int i_ = 0; i_ < 2; i_++)                                         \
            gload16(pA + (RC) + sAo[i_], Ld_ + ((i_ * 256 + tid) << 4));       \
        _Pragma("unroll")                                                      \
        for (int i_ = 0; i_ < 4; i_++)                                         \
            gload16(pB + (RC) + sBo[i_], Ld_ + 8192 + ((i_ * 256 + tid) << 4));\
    } while (0)
    STG1(0, 0);
    __syncthreads();
    int cur = 0;
    for (int step = 0; step < NST1; step++) {
        if (step + 1 < NST1) STG1((cur ^ 1) * 24576, (step + 1) << 7);
        const char* LA = ldsb + cur * 24576;
        const char* LB = LA + 8192;
#pragma unroll
        for (int kc = 0; kc < 4; kc++) {
            int c = kc * 2 + kg;
            h8 a0 = *(const h8*)(LA + ((r0 * 8 + (c ^ x)) << 4));
            h8 b0 = *(const h8*)(LB + ((q0 * 8 + (c ^ x)) << 4));
            h8 b1 = *(const h8*)(LB + (((q0 + 32) * 8 + (c ^ x)) << 4));
            acc0 = MFMA32(a0, b0, acc0);
            acc1 = MFMA32(a0, b1, acc1);
        }
        __syncthreads();
        cur ^= 1;
    }
#undef STG1
    // epilogue: inline phi + LS-combine; wave owns rows m0+wm..+31, cols n0+wn..+63
    int bb = mt;                            // 64-row tile aligns with batch dim
    int colk = lane & 31, rb4 = (lane >> 5) * 4;
    float cn = cnt[bb];
    float cpJ[2], spJ[2], rcJ[2], rsJ[2];
#pragma unroll
    for (int J = 0; J < 2; J++) {
        int k2 = n0 + wn + 32 * J + colk;
        int k = k2 >> 1;
        float s2 = 0.f, c2 = 0.f;
#pragma unroll
        for (int c = 0; c < 8; c++) {
            s2 += partS[(size_t)(c * 8 + bb) * KP + k];
            c2 += partC[(size_t)(c * 8 + bb) * KP + k];
        }
        float phi = 0.5f * atan2f(s2, c2);
        float cp = cosf(phi), sp = sinf(phi);
        float A = 0.5f * (cn + c2), D = 0.5f * (cn - c2), E = 0.5f * s2;
        cpJ[J] = cp; spJ[J] = sp;
        rcJ[J] = 1.f / (cp * cp * A + 2.f * cp * sp * E + sp * sp * D);
        rsJ[J] = 1.f / (sp * sp * A - 2.f * cp * sp * E + cp * cp * D);
    }
#define EPI1(ACC, J) {                                                         \
        int k2 = n0 + wn + 32 * (J) + colk;                                    \
        float cp = cpJ[J], sp = spJ[J];                                        \
        float rc_ = rcJ[J], rs_ = rsJ[J];                                      \
        int par = k2 & 1;                                                      \
        _Pragma("unroll")                                                      \
        for (int reg = 0; reg < 16; reg++) {                                   \
            float own = (ACC)[reg];                                            \
            float oth = __shfl_xor(own, 1);                                    \
            float p = par ? oth : own, q = par ? own : oth;                    \
            float cc = (cp * p + sp * q) * rc_;                                \
            float sc = (cp * q - sp * p) * rs_;                                \
            float val = par ? (sp * cc + cp * sc) : (cp * cc - sp * sc);       \
            int row = m0 + wm + rb4 + (reg & 3) + 8 * (reg >> 2);              \
            Wout[(size_t)row * K2P + k2] = (_Float16)val;                      \
        } }
    EPI1(acc0, 0); EPI1(acc1, 1);
#undef EPI1
}

// ---------------- GEMM2: 128(m) x 64(t) tiles, split-K=8; rpart f16 ----------------
// waves 2x2: wave tile 64(m) x 32(t); tt cycles fastest (A-panel L2 locality)
__global__ __launch_bounds__(256, 3) void gemm2x(
    const _Float16* __restrict__ Wm, const _Float16* __restrict__ ZT,
    _Float16* __restrict__ rpart) {
    __shared__ _Float16 lds[24576];   // 48KB: 2 bufs x (A 16KB | B 8KB)
    char* ldsb = (char*)lds;
    int bx = blockIdx.x;                 // 640 = 8 XCD * 80; one sk per XCD
    int sk = bx & 7;
    int g2 = bx >> 3;                    // 0..79
    int mt = g2 / 20, tt = g2 % 20;      // tt fastest: 20 consecutive blocks share A-panel
    int m0 = mt * 128, t0 = tt * 64;
    int tid = threadIdx.x, lane = tid & 63, wv = tid >> 6;
    int ra = lane & 31, kg = lane >> 5, x = ra & 7;
    int wm = (wv & 1) * 64, wn = (wv >> 1) * 32;
    int r0 = wm + ra, q0 = wn + ra;
    f32x16 acc0 = Z16v, acc1 = Z16v;
    int sAo[4], sBo[2];
#pragma unroll
    for (int i = 0; i < 4; i++) {
        int g8 = i * 256 + tid;
        int r = g8 >> 3, c = g8 & 7;
        sAo[i] = r * 19456 + ((c ^ (r & 7)) << 4);
    }
#pragma unroll
    for (int i = 0; i < 2; i++) {
        int g8 = i * 256 + tid;
        int r = g8 >> 3, c = g8 & 7;
        sBo[i] = r * 19456 + ((c ^ (r & 7)) << 4);
    }
    const char* pA = (const char*)Wm + (size_t)m0 * 19456 + sk * 2432;
    const char* pB = (const char*)ZT + (size_t)t0 * 19456 + sk * 2432;
#define STG2(BUFOFF, RC) do {                                                  \
        char* Ld_ = ldsb + (BUFOFF);                                           \
        _Pragma("unroll")                                                      \
        for (int i_ = 0; i_ < 4; i_++)                                         \
            gload16(pA + (RC) + sAo[i_], Ld_ + ((i_ * 256 + tid) << 4));       \
        _Pragma("unroll")                                                      \
        for (int i_ = 0; i_ < 2; i_++)                                         \
            gload16(pB + (RC) + sBo[i_], Ld_ + 16384 + ((i_ * 256 + tid) << 4));\
    } while (0)
    STG2(0, 0);
    __syncthreads();
    int cur = 0;
    for (int step = 0; step < NST2; step++) {
        if (step + 1 < NST2) STG2((cur ^ 1) * 24576, (step + 1) << 7);
        const char* LA = ldsb + cur * 24576;
        const char* LB = LA + 16384;
#pragma unroll
        for (int kc = 0; kc < 4; kc++) {
            int c = kc * 2 + kg;
            h8 a0 = *(const h8*)(LA + ((r0 * 8 + (c ^ x)) << 4));
            h8 a1 = *(const h8*)(LA + (((r0 + 32) * 8 + (c ^ x)) << 4));
            h8 b0 = *(const h8*)(LB + ((q0 * 8 + (c ^ x)) << 4));
            acc0 = MFMA32(a0, b0, acc0);
            acc1 = MFMA32(a1, b0, acc1);
        }
        __syncthreads();
        cur ^= 1;
    }
#undef STG2
    int colk = lane & 31, rb4 = (lane >> 5) * 4;
    int t = t0 + wn + colk;
#define EPI2(ACC, I) {                                                         \
        _Pragma("unroll")                                                      \
        for (int reg = 0; reg < 16; reg++) {                                   \
            int row = m0 + wm + 32 * (I) + rb4 + (reg & 3) + 8 * (reg >> 2);   \
            rpart[(size_t)(sk * M_ + row) * TP2 + t] = (_Float16)(ACC)[reg];   \
        } }
    EPI2(acc0, 0); EPI2(acc1, 1);
#undef EPI2
}

// ---------------- normalize + select (f16 rpart) ----------------
__global__ __launch_bounds__(256) void norm3_kernel(
    const _Float16* __restrict__ rpart, const float* __restrict__ data,
    const float* __restrict__ mf, const float* __restrict__ cnt,
    float* __restrict__ out) {
    __shared__ float rsum[T_];
    __shared__ float4 red4[256];
    __shared__ float s_scale;
    int bc = blockIdx.x, b = bc >> 6;
    const size_t rbase = (size_t)bc * TP2;
    const size_t dbase = (size_t)bc * T_;
    const size_t rstr = (size_t)M_ * TP2;
    float sr = 0.f, srr = 0.f, sd = 0.f, sdd = 0.f;
    for (int t = threadIdx.x; t < T_; t += 256) {
        float r = 0.f;
#pragma unroll
        for (int s = 0; s < SPLITK; s++) r += (float)rpart[s * rstr + rbase + t];
        rsum[t] = r;
        float m = mf[b * T_ + t];
        float xv = data[dbase + t];
        sr += r; srr += r * r; sd += xv * m; sdd += xv * xv * m;
    }
    red4[threadIdx.x] = make_float4(sr, srr, sd, sdd);
    __syncthreads();
    for (int w = 128; w > 0; w >>= 1) {
        if (threadIdx.x < w) {
            float4 a = red4[threadIdx.x], c = red4[threadIdx.x + w];
            red4[threadIdx.x] = make_float4(a.x + c.x, a.y + c.y, a.z + c.z, a.w + c.w);
        }
        __syncthreads();
    }
    if (threadIdx.x == 0) {
        float4 v = red4[0];
        float cn = cnt[b];
        float varr = (v.y - v.x * v.x / (float)T_) / (float)(T_ - 1);
        float vard = (v.w - v.z * v.z / cn) / (cn - 1.f);
        s_scale = sqrtf(vard / varr);
    }
    __syncthreads();
    float scale = s_scale;
    for (int t = threadIdx.x; t < T_; t += 256) {
        float m = mf[b * T_ + t];
        out[dbase + t] = (m > 0.5f) ? data[dbase + t] : rsum[t] * scale;
    }
}

extern "C" void kernel_launch(void* const* d_in, const int* in_sizes, int n_in,
                              void* d_out, int out_size, void* d_ws, size_t ws_size,
                              hipStream_t stream) {
    const float* data = (const float*)d_in[0];
    const void* mask = d_in[1];
    float* out = (float*)d_out;

    // Replicate numpy arange length computation exactly (double precision).
    const double timespan = 1.0 * (T_ + 1) - 1.0;               // 1200
    const double fstep = 1.0 / (timespan * 8.0);                // OSFREQ = 8
    const double stop = (1.0 * (double)T_) / (2.0 * timespan) + fstep;
    const int K = (int)ceil((stop - fstep) / fstep);            // 4800 (or 4801)

    char* w = (char*)d_ws;
    auto alloc = [&](size_t nbytes) {
        char* p = w;
        w += ((nbytes + 255) / 256) * 256;
        return p;
    };
    float*     mf    = (float*)    alloc((size_t)B_ * T_ * 4);
    float*     cnt   = (float*)    alloc(B_ * 4);
    float2*    rot1  = (float2*)   alloc((size_t)KP * 8);
    float2*    rot8  = (float2*)   alloc((size_t)KP * 8);
    float2*    rot32 = (float2*)   alloc((size_t)KP * 8);
    float2*    rot64 = (float2*)   alloc((size_t)KP * 8);
    float2*    rot2  = (float2*)   alloc((size_t)KP * 8);
    float2*    rot304= (float2*)   alloc((size_t)KP * 8);
    float*     partS = (float*)    alloc((size_t)64 * KP * 4);
    float*     partC = (float*)    alloc((size_t)64 * KP * 4);
    _Float16*  dm_h  = (_Float16*) alloc((size_t)M_ * TP2 * 2);
    _Float16*  Z     = (_Float16*) alloc((size_t)K2P * TP2 * 2);
    _Float16*  ZT    = (_Float16*) alloc((size_t)TP2 * K2P * 2);
    _Float16*  W     = (_Float16*) alloc((size_t)M_ * K2P * 2);
    _Float16*  rpart = (_Float16*) alloc((size_t)SPLITK * M_ * TP2 * 2);
    (void)ws_size; (void)in_sizes; (void)n_in; (void)out_size;

    seed_kernel<<<125, 256, 0, stream>>>(mask, mf, cnt, rot1, rot8, rot32,
                                         rot64, rot2, rot304, fstep);
    prep2_kernel<<<1992, 256, 0, stream>>>(data, mf, rot1, rot8, rot32, rot64,
                                           rot2, rot304, dm_h, partS, partC, Z, ZT, K);
    gemm1x<<<608, 256, 0, stream>>>(dm_h, Z, partS, partC, cnt, W);
    gemm2x<<<640, 256, 0, stream>>>(W, ZT, rpart);
    norm3_kernel<<<M_, 256, 0, stream>>>(rpart, data, mf, cnt, out);
}

// Round 20
// 88.770 us; speedup vs baseline: 1.0374x; 1.0081x over previous
//
#include <hip/hip_runtime.h>
#include <math.h>

#define B_ 8
#define C_ 64
#define M_ 512            // B_*C_
#define T_ 1200
#define TP2 1280          // T padded to 128
#define KP 4864           // K padded (K = 4800)
#define K2P 9728          // 2*KP interleaved cos/sin
#define SPLITK 8
#define KCH 1216          // K2P/SPLITK halves
#define NST1 20           // TP2/64 reduction steps (gemm1)
#define NST2 19           // KCH/64 reduction steps (gemm2)
#define TCH 152           // tau t-chunk length (8*152 = 1216)

#ifndef M_PI
#define M_PI 3.14159265358979323846
#endif

typedef _Float16 h8 __attribute__((ext_vector_type(8)));
typedef float f32x16 __attribute__((ext_vector_type(16)));
union H8 { h8 h; float4 v; _Float16 e[8]; };
union HP { _Float16 hh[2]; unsigned u; };
union F4U { float4 v; float f[4]; };

#define Z16v {0.f,0.f,0.f,0.f,0.f,0.f,0.f,0.f,0.f,0.f,0.f,0.f,0.f,0.f,0.f,0.f}
#define MFMA32(a, b, c) __builtin_amdgcn_mfma_f32_32x32x16_f16(a, b, c, 0, 0, 0)

__device__ __forceinline__ float2 cmul(float2 a, float2 b) {
    return make_float2(a.x * b.x - a.y * b.y, a.y * b.x + a.x * b.y);
}

// async global->LDS, 16B per lane (dest resolves to wave base + lane*16)
__device__ __forceinline__ void gload16(const void* g, void* l) {
    __builtin_amdgcn_global_load_lds(
        (const __attribute__((address_space(1))) unsigned int*)g,
        (__attribute__((address_space(3))) unsigned int*)l, 16, 0, 0);
}

__device__ int detect_mode(const void* mask_raw) {
    __shared__ int sb0, sb1;
    if (threadIdx.x == 0) { sb0 = 0; sb1 = 0; }
    __syncthreads();
    const unsigned* wi = (const unsigned*)mask_raw;
    const float* wf = (const float*)mask_raw;
    int nw = (B_ * T_) >> 2;
    int badI = 0, badF = 0;
    for (int i = threadIdx.x; i < nw; i += blockDim.x) {
        unsigned v = wi[i];
        badI |= (v > 1u);
        float f = wf[i];
        badF |= !(f == 0.0f || f == 1.0f);
    }
    if (badI) sb0 = 1;
    if (badF) sb1 = 1;
    __syncthreads();
    return (!sb0) ? 0 : ((!sb1) ? 1 : 2);
}

__device__ __forceinline__ float mval(const void* mask_raw, int mode, int idx) {
    if (mode == 0) return (float)((const int*)mask_raw)[idx];
    if (mode == 1) return ((const float*)mask_raw)[idx];
    return (float)((const unsigned char*)mask_raw)[idx];
}

// ---------------- K1 seed: rot tables (0..113) | mf (114..123) | cnt (124) ----------------
__global__ __launch_bounds__(256) void seed_kernel(
    const void* __restrict__ mask, float* __restrict__ mf, float* __restrict__ cnt,
    float2* __restrict__ rot1, float2* __restrict__ rot8,
    float2* __restrict__ rot32, float2* __restrict__ rot64,
    float2* __restrict__ rot2, float2* __restrict__ rot304, double fstep) {
    int bx = blockIdx.x, tid = threadIdx.x;
    if (bx < 114) {
        int tb = bx / 19;
        int k = (bx % 19) * 256 + tid;     // < 4864
        double om = 2.0 * M_PI * (fstep + (double)k * fstep);
        double w = (double)((float)om);    // reference rounds omega to f32
        double mult = (tb == 0) ? 1.0 : (tb == 1) ? 8.0 : (tb == 2) ? 32.0
                    : (tb == 3) ? 64.0 : (tb == 4) ? 2.0 : 304.0;
        double s, c;
        sincos(mult * w, &s, &c);
        float2 v = make_float2((float)c, (float)s);
        if (tb == 0)      rot1[k] = v;
        else if (tb == 1) rot8[k] = v;
        else if (tb == 2) rot32[k] = v;
        else if (tb == 3) rot64[k] = v;
        else if (tb == 4) rot2[k] = v;
        else              rot304[k] = v;
        return;
    }
    int mode = detect_mode(mask);
    if (bx < 124) {
        // mf convert, vectorized
        int i = ((bx - 114) * 256 + tid) * 4;   // 10 blocks cover 9600
        if (i >= B_ * T_) return;
        F4U o;
        if (mode == 0) {
            int4 v = *(const int4*)((const int*)mask + i);
            o.f[0] = (float)v.x; o.f[1] = (float)v.y; o.f[2] = (float)v.z; o.f[3] = (float)v.w;
        } else if (mode == 1) {
            o.v = *(const float4*)((const float*)mask + i);
        } else {
            unsigned v = *(const unsigned*)((const unsigned char*)mask + i);
            o.f[0] = (float)(v & 0xff); o.f[1] = (float)((v >> 8) & 0xff);
            o.f[2] = (float)((v >> 16) & 0xff); o.f[3] = (float)((v >> 24) & 0xff);
        }
        *(float4*)&mf[i] = o.v;
        return;
    }
    // bx == 124: cnt via per-b block reduction over raw mask (no atomics)
    {
        __shared__ float red[256];
        for (int b = 0; b < B_; b++) {
            float s = 0.f;
            for (int t = tid; t < T_; t += 256) s += mval(mask, mode, b * T_ + t);
            red[tid] = s; __syncthreads();
            for (int w = 128; w > 0; w >>= 1) {
                if (tid < w) red[tid] += red[tid + w];
                __syncthreads();
            }
            if (tid == 0) cnt[b] = red[0];
            __syncthreads();
        }
    }
}

// ---------------- K2 prep2: dm (0..319) | tau (320..471) | basisD (472..1991) ----------------
__global__ __launch_bounds__(256) void prep2_kernel(
    const float* __restrict__ data, const float* __restrict__ mf,
    const float2* __restrict__ rot1t, const float2* __restrict__ rot8t,
    const float2* __restrict__ rot32t, const float2* __restrict__ rot64t,
    const float2* __restrict__ rot2t, const float2* __restrict__ rot304t,
    _Float16* __restrict__ dm, float* __restrict__ partS, float* __restrict__ partC,
    _Float16* __restrict__ Zb, _Float16* __restrict__ ZT, int K) {
    __shared__ float mfS[B_][TCH];            // tau role
    __shared__ _Float16 sZ[128 * 80];         // basisD role
    __shared__ _Float16 sZT[64 * 136];        // basisD role
    int bx = blockIdx.x, tid = threadIdx.x;
    if (bx < 320) {
        // dm: dm[bc][TP2] = f16(data*mf), 8 halves/thread
        int base = (bx * 256 + tid) * 8;
        int t = base % TP2, bc = base / TP2;
        H8 o;
        if (t < T_) {
            int b = bc >> 6;
            F4U d0, d1, m0, m1;
            d0.v = *(const float4*)&data[bc * T_ + t];
            d1.v = *(const float4*)&data[bc * T_ + t + 4];
            m0.v = *(const float4*)&mf[b * T_ + t];
            m1.v = *(const float4*)&mf[b * T_ + t + 4];
#pragma unroll
            for (int e = 0; e < 4; e++) {
                o.e[e]     = (_Float16)(d0.f[e] * m0.f[e]);
                o.e[e + 4] = (_Float16)(d1.f[e] * m1.f[e]);
            }
        } else {
#pragma unroll
            for (int e = 0; e < 8; e++) o.e[e] = (_Float16)0.f;
        }
        *(float4*)&dm[base] = o.v;
        return;
    }
    if (bx < 472) {
        // tau partials
        int i0 = bx - 320;                    // 0..151
        int kb = i0 % 19, chunk = i0 / 19;    // 19 k-blocks x 8 chunks
        for (int i = tid; i < B_ * TCH; i += 256) {
            int b = i / TCH, tt = i % TCH;
            int t = chunk * TCH + tt;
            mfS[b][tt] = (t < T_) ? mf[b * T_ + t] : 0.f;
        }
        __syncthreads();
        int k = kb * 256 + tid;
        float2 r2 = rot2t[k];
        float2 r = r2;
        {   // * rot304^chunk
            int e = chunk;
            float2 p = rot304t[k];
            while (e) { if (e & 1) r = cmul(r, p); p = cmul(p, p); e >>= 1; }
        }
        float s2a[B_], c2a[B_];
#pragma unroll
        for (int b = 0; b < B_; b++) { s2a[b] = 0.f; c2a[b] = 0.f; }
        for (int tt = 0; tt < TCH; tt++) {
            float sv = r.y, cv = r.x;
#pragma unroll
            for (int b = 0; b < B_; b++) {
                float m = mfS[b][tt];        // uniform address -> broadcast
                s2a[b] = fmaf(m, sv, s2a[b]);
                c2a[b] = fmaf(m, cv, c2a[b]);
            }
            r = cmul(r, r2);
        }
#pragma unroll
        for (int b = 0; b < B_; b++) {
            partS[(size_t)(chunk * 8 + b) * KP + k] = s2a[b];
            partC[(size_t)(chunk * 8 + b) * KP + k] = c2a[b];
        }
        return;
    }
    // basisD: Z[k2][t], ZT[t][k2], 64k x 64t tiles
    {
        int i0 = bx - 472;                    // 0..1519
        int kb = i0 / 20, tb = i0 % 20;
        int k0 = kb * 64, t0 = tb * 64;
        int kk = tid >> 2, tq = tid & 3;
        int k = k0 + kk;
        float2 r1 = rot1t[k];
        float2 acc = r1;                      // angle w*1
        {   // * rot8^tq
            float2 p = rot8t[k];
            if (tq & 1) acc = cmul(acc, p);
            p = cmul(p, p);
            if (tq & 2) acc = cmul(acc, p);
        }
        {   // * rot64^tb
            int e = tb;
            float2 p = rot64t[k];
            while (e) { if (e & 1) acc = cmul(acc, p); p = cmul(p, p); e >>= 1; }
        }
        bool kv = (k < K);
        float2 r32 = rot32t[k];
#pragma unroll
        for (int j = 0; j < 2; j++) {
            float2 r = acc;
            H8 hc, hs;
#pragma unroll
            for (int d = 0; d < 8; d++) {
                int tl = tq * 8 + j * 32 + d;
                bool ok = kv && (t0 + tl < T_);
                float c = ok ? r.x : 0.f, s = ok ? r.y : 0.f;
                hc.e[d] = (_Float16)c; hs.e[d] = (_Float16)s;
                HP pk; pk.hh[0] = hc.e[d]; pk.hh[1] = hs.e[d];
                *(unsigned*)&sZT[tl * 136 + 2 * kk] = pk.u;
                r = cmul(r, r1);
            }
            int ch = tq + 4 * j;              // chunk 0..7
            int rc = 2 * kk, rs = 2 * kk + 1;
            *(float4*)&sZ[rc * 80 + ((ch ^ (rc & 7)) << 3)] = hc.v;
            *(float4*)&sZ[rs * 80 + ((ch ^ (rs & 7)) << 3)] = hs.v;
            acc = cmul(acc, r32);
        }
        __syncthreads();
        // Z out: 128 rows x 128B
        {
            int c8 = tid & 7, rr = tid >> 3;  // rr 0..31
#pragma unroll
            for (int p = 0; p < 4; p++) {
                int row = p * 32 + rr;
                float4 v = *(const float4*)&sZ[row * 80 + ((c8 ^ (row & 7)) << 3)];
                *(float4*)&Zb[(size_t)(2 * k0 + row) * TP2 + t0 + c8 * 8] = v;
            }
        }
        // ZT out: 64 rows x 256B
        {
            int c16 = tid & 15, rr = tid >> 4; // rr 0..15
#pragma unroll
            for (int p = 0; p < 4; p++) {
                int row = p * 16 + rr;
                float4 v = *(const float4*)&sZT[row * 136 + c16 * 8];
                *(float4*)&ZT[(size_t)(t0 + row) * K2P + 2 * k0 + c16 * 8] = v;
            }
        }
    }
}

// ---------------- GEMM1: 64(m) x 128(k2) tiles, fused phi + LS-combine ----------------
// waves 2x2: wave tile 32(m) x 64(k2); 8 MFMA/step/wave
__global__ __launch_bounds__(256, 3) void gemm1x(
    const _Float16* __restrict__ dm, const _Float16* __restrict__ Zb,
    const float* __restrict__ partS, const float* __restrict__ partC,
    const float* __restrict__ cnt,
    _Float16* __restrict__ Wout) {
    __shared__ _Float16 lds[24576];   // 48KB: 2 bufs x (A 8KB | B 16KB)
    char* ldsb = (char*)lds;
    int bx = blockIdx.x;                    // 608 = 8 XCD * 76
    int g = (bx & 7) * 76 + (bx >> 3);      // bijective, XCD-chunked
    int mt = g & 7, nt = g >> 3;
    int m0 = mt * 64, n0 = nt * 128;
    int tid = threadIdx.x, lane = tid & 63, wv = tid >> 6;
    int ra = lane & 31, kg = lane >> 5, x = ra & 7;
    int wm = (wv & 1) * 32, wn = (wv >> 1) * 64;
    int r0 = wm + ra, q0 = wn + ra;
    f32x16 acc0 = Z16v, acc1 = Z16v;
    int sAo[2], sBo[4];
#pragma unroll
    for (int i = 0; i < 2; i++) {
        int g8 = i * 256 + tid;
        int r = g8 >> 3, c = g8 & 7;
        sAo[i] = r * 2560 + ((c ^ (r & 7)) << 4);
    }
#pragma unroll
    for (int i = 0; i < 4; i++) {
        int g8 = i * 256 + tid;
        int r = g8 >> 3, c = g8 & 7;
        sBo[i] = r * 2560 + ((c ^ (r & 7)) << 4);
    }
    const char* pA = (const char*)dm + (size_t)m0 * 2560;
    const char* pB = (const char*)Zb + (size_t)n0 * 2560;
#define STG1(BUFOFF, RC) do {                                                  \
        char* Ld_ = ldsb + (BUFOFF);                                           \
        _Pragma("unroll")                                                      \
        for (int i_ = 0; i_ < 2; i_++)                                         \
            gload16(pA + (RC) + sAo[i_], Ld_ + ((i_ * 256 + tid) << 4));       \
        _Pragma("unroll")                                                      \
        for (int i_ = 0; i_ < 4; i_++)                                         \
            gload16(pB + (RC) + sBo[i_], Ld_ + 8192 + ((i_ * 256 + tid) << 4));\
    } while (0)
    STG1(0, 0);
    __syncthreads();
    int cur = 0;
    for (int step = 0; step < NST1; step++) {
        if (step + 1 < NST1) STG1((cur ^ 1) * 24576, (step + 1) << 7);
        const char* LA = ldsb + cur * 24576;
        const char* LB = LA + 8192;
#pragma unroll
        for (int kc = 0; kc < 4; kc++) {
            int c = kc * 2 + kg;
            h8 a0 = *(const h8*)(LA + ((r0 * 8 + (c ^ x)) << 4));
            h8 b0 = *(const h8*)(LB + ((q0 * 8 + (c ^ x)) << 4));
            h8 b1 = *(const h8*)(LB + (((q0 + 32) * 8 + (c ^ x)) << 4));
            acc0 = MFMA32(a0, b0, acc0);
            acc1 = MFMA32(a0, b1, acc1);
        }
        __syncthreads();
        cur ^= 1;
    }
#undef STG1
    // epilogue: inline phi + LS-combine; wave owns rows m0+wm..+31, cols n0+wn..+63
    int bb = mt;                            // 64-row tile aligns with batch dim
    int colk = lane & 31, rb4 = (lane >> 5) * 4;
    float cn = cnt[bb];
    float cpJ[2], spJ[2], rcJ[2], rsJ[2];
#pragma unroll
    for (int J = 0; J < 2; J++) {
        int k2 = n0 + wn + 32 * J + colk;
        int k = k2 >> 1;
        float s2 = 0.f, c2 = 0.f;
#pragma unroll
        for (int c = 0; c < 8; c++) {
            s2 += partS[(size_t)(c * 8 + bb) * KP + k];
            c2 += partC[(size_t)(c * 8 + bb) * KP + k];
        }
        float phi = 0.5f * atan2f(s2, c2);
        float cp = cosf(phi), sp = sinf(phi);
        float A = 0.5f * (cn + c2), D = 0.5f * (cn - c2), E = 0.5f * s2;
        cpJ[J] = cp; spJ[J] = sp;
        rcJ[J] = 1.f / (cp * cp * A + 2.f * cp * sp * E + sp * sp * D);
        rsJ[J] = 1.f / (sp * sp * A - 2.f * cp * sp * E + cp * cp * D);
    }
#define EPI1(ACC, J) {                                                         \
        int k2 = n0 + wn + 32 * (J) + colk;                                    \
        float cp = cpJ[J], sp = spJ[J];                                        \
        float rc_ = rcJ[J], rs_ = rsJ[J];                                      \
        int par = k2 & 1;                                                      \
        _Pragma("unroll")                                                      \
        for (int reg = 0; reg < 16; reg++) {                                   \
            float own = (ACC)[reg];                                            \
            float oth = __shfl_xor(own, 1);                                    \
            float p = par ? oth : own, q = par ? own : oth;                    \
            float cc = (cp * p + sp * q) * rc_;                                \
            float sc = (cp * q - sp * p) * rs_;                                \
            float val = par ? (sp * cc + cp * sc) : (cp * cc - sp * sc);       \
            int row = m0 + wm + rb4 + (reg & 3) + 8 * (reg >> 2);              \
            Wout[(size_t)row * K2P + k2] = (_Float16)val;                      \
        } }
    EPI1(acc0, 0); EPI1(acc1, 1);
#undef EPI1
}

// ---------------- GEMM2: 128(m) x 64(t) tiles, split-K=8; rpart f16 ----------------
// waves 2x2: wave tile 64(m) x 32(t); 8 MFMA/step/wave
__global__ __launch_bounds__(256, 3) void gemm2x(
    const _Float16* __restrict__ Wm, const _Float16* __restrict__ ZT,
    _Float16* __restrict__ rpart) {
    __shared__ _Float16 lds[24576];   // 48KB: 2 bufs x (A 16KB | B 8KB)
    char* ldsb = (char*)lds;
    int bx = blockIdx.x;                 // 640 = 8 XCD * 80; one sk per XCD
    int sk = bx & 7;
    int g2 = bx >> 3;                    // 0..79
    int mt = g2 & 3, tt = g2 >> 2;       // mt 0..3, tt 0..19
    int m0 = mt * 128, t0 = tt * 64;
    int tid = threadIdx.x, lane = tid & 63, wv = tid >> 6;
    int ra = lane & 31, kg = lane >> 5, x = ra & 7;
    int wm = (wv & 1) * 64, wn = (wv >> 1) * 32;
    int r0 = wm + ra, q0 = wn + ra;
    f32x16 acc0 = Z16v, acc1 = Z16v;
    int sAo[4], sBo[2];
#pragma unroll
    for (int i = 0; i < 4; i++) {
        int g8 = i * 256 + tid;
        int r = g8 >> 3, c = g8 & 7;
        sAo[i] = r * 19456 + ((c ^ (r & 7)) << 4);
    }
#pragma unroll
    for (int i = 0; i < 2; i++) {
        int g8 = i * 256 + tid;
        int r = g8 >> 3, c = g8 & 7;
        sBo[i] = r * 19456 + ((c ^ (r & 7)) << 4);
    }
    const char* pA = (const char*)Wm + (size_t)m0 * 19456 + sk * 2432;
    const char* pB = (const char*)ZT + (size_t)t0 * 19456 + sk * 2432;
#define STG2(BUFOFF, RC) do {                                                  \
        char* Ld_ = ldsb + (BUFOFF);                                           \
        _Pragma("unroll")                                                      \
        for (int i_ = 0; i_ < 4; i_++)                                         \
            gload16(pA + (RC) + sAo[i_], Ld_ + ((i_ * 256 + tid) << 4));       \
        _Pragma("unroll")                                                      \
        for (int i_ = 0; i_ < 2; i_++)                                         \
            gload16(pB + (RC) + sBo[i_], Ld_ + 16384 + ((i_ * 256 + tid) << 4));\
    } while (0)
    STG2(0, 0);
    __syncthreads();
    int cur = 0;
    for (int step = 0; step < NST2; step++) {
        if (step + 1 < NST2) STG2((cur ^ 1) * 24576, (step + 1) << 7);
        const char* LA = ldsb + cur * 24576;
        const char* LB = LA + 16384;
#pragma unroll
        for (int kc = 0; kc < 4; kc++) {
            int c = kc * 2 + kg;
            h8 a0 = *(const h8*)(LA + ((r0 * 8 + (c ^ x)) << 4));
            h8 a1 = *(const h8*)(LA + (((r0 + 32) * 8 + (c ^ x)) << 4));
            h8 b0 = *(const h8*)(LB + ((q0 * 8 + (c ^ x)) << 4));
            acc0 = MFMA32(a0, b0, acc0);
            acc1 = MFMA32(a1, b0, acc1);
        }
        __syncthreads();
        cur ^= 1;
    }
#undef STG2
    int colk = lane & 31, rb4 = (lane >> 5) * 4;
    int t = t0 + wn + colk;
#define EPI2(ACC, I) {                                                         \
        _Pragma("unroll")                                                      \
        for (int reg = 0; reg < 16; reg++) {                                   \
            int row = m0 + wm + 32 * (I) + rb4 + (reg & 3) + 8 * (reg >> 2);   \
            rpart[(size_t)(sk * M_ + row) * TP2 + t] = (_Float16)(ACC)[reg];   \
        } }
    EPI2(acc0, 0); EPI2(acc1, 1);
#undef EPI2
}

// ---------------- normalize + select (f16 rpart) ----------------
__global__ __launch_bounds__(256) void norm3_kernel(
    const _Float16* __restrict__ rpart, const float* __restrict__ data,
    const float* __restrict__ mf, const float* __restrict__ cnt,
    float* __restrict__ out) {
    __shared__ float rsum[T_];
    __shared__ float4 red4[256];
    __shared__ float s_scale;
    int bc = blockIdx.x, b = bc >> 6;
    const size_t rbase = (size_t)bc * TP2;
    const size_t dbase = (size_t)bc * T_;
    const size_t rstr = (size_t)M_ * TP2;
    float sr = 0.f, srr = 0.f, sd = 0.f, sdd = 0.f;
    for (int t = threadIdx.x; t < T_; t += 256) {
        float r = 0.f;
#pragma unroll
        for (int s = 0; s < SPLITK; s++) r += (float)rpart[s * rstr + rbase + t];
        rsum[t] = r;
        float m = mf[b * T_ + t];
        float xv = data[dbase + t];
        sr += r; srr += r * r; sd += xv * m; sdd += xv * xv * m;
    }
    red4[threadIdx.x] = make_float4(sr, srr, sd, sdd);
    __syncthreads();
    for (int w = 128; w > 0; w >>= 1) {
        if (threadIdx.x < w) {
            float4 a = red4[threadIdx.x], c = red4[threadIdx.x + w];
            red4[threadIdx.x] = make_float4(a.x + c.x, a.y + c.y, a.z + c.z, a.w + c.w);
        }
        __syncthreads();
    }
    if (threadIdx.x == 0) {
        float4 v = red4[0];
        float cn = cnt[b];
        float varr = (v.y - v.x * v.x / (float)T_) / (float)(T_ - 1);
        float vard = (v.w - v.z * v.z / cn) / (cn - 1.f);
        s_scale = sqrtf(vard / varr);
    }
    __syncthreads();
    float scale = s_scale;
    for (int t = threadIdx.x; t < T_; t += 256) {
        float m = mf[b * T_ + t];
        out[dbase + t] = (m > 0.5f) ? data[dbase + t] : rsum[t] * scale;
    }
}

extern "C" void kernel_launch(void* const* d_in, const int* in_sizes, int n_in,
                              void* d_out, int out_size, void* d_ws, size_t ws_size,
                              hipStream_t stream) {
    const float* data = (const float*)d_in[0];
    const void* mask = d_in[1];
    float* out = (float*)d_out;

    // Replicate numpy arange length computation exactly (double precision).
    const double timespan = 1.0 * (T_ + 1) - 1.0;               // 1200
    const double fstep = 1.0 / (timespan * 8.0);                // OSFREQ = 8
    const double stop = (1.0 * (double)T_) / (2.0 * timespan) + fstep;
    const int K = (int)ceil((stop - fstep) / fstep);            // 4800 (or 4801)

    char* w = (char*)d_ws;
    auto alloc = [&](size_t nbytes) {
        char* p = w;
        w += ((nbytes + 255) / 256) * 256;
        return p;
    };
    float*     mf    = (float*)    alloc((size_t)B_ * T_ * 4);
    float*     cnt   = (float*)    alloc(B_ * 4);
    float2*    rot1  = (float2*)   alloc((size_t)KP * 8);
    float2*    rot8  = (float2*)   alloc((size_t)KP * 8);
    float2*    rot32 = (float2*)   alloc((size_t)KP * 8);
    float2*    rot64 = (float2*)   alloc((size_t)KP * 8);
    float2*    rot2  = (float2*)   alloc((size_t)KP * 8);
    float2*    rot304= (float2*)   alloc((size_t)KP * 8);
    float*     partS = (float*)    alloc((size_t)64 * KP * 4);
    float*     partC = (float*)    alloc((size_t)64 * KP * 4);
    _Float16*  dm_h  = (_Float16*) alloc((size_t)M_ * TP2 * 2);
    _Float16*  Z     = (_Float16*) alloc((size_t)K2P * TP2 * 2);
    _Float16*  ZT    = (_Float16*) alloc((size_t)TP2 * K2P * 2);
    _Float16*  W     = (_Float16*) alloc((size_t)M_ * K2P * 2);
    _Float16*  rpart = (_Float16*) alloc((size_t)SPLITK * M_ * TP2 * 2);
    (void)ws_size; (void)in_sizes; (void)n_in; (void)out_size;

    seed_kernel<<<125, 256, 0, stream>>>(mask, mf, cnt, rot1, rot8, rot32,
                                         rot64, rot2, rot304, fstep);
    prep2_kernel<<<1992, 256, 0, stream>>>(data, mf, rot1, rot8, rot32, rot64,
                                           rot2, rot304, dm_h, partS, partC, Z, ZT, K);
    gemm1x<<<608, 256, 0, stream>>>(dm_h, Z, partS, partC, cnt, W);
    gemm2x<<<640, 256, 0, stream>>>(W, ZT, rpart);
    norm3_kernel<<<M_, 256, 0, stream>>>(rpart, data, mf, cnt, out);
}